// Round 8
// baseline (391.869 us; speedup 1.0000x reference)
//
#include <hip/hip_runtime.h>
#include <hip/hip_fp16.h>
#include <math.h>

#define DIM    512
#define NTHR   512
#define NKK    256          // pair-rows (2 matrix rows per pair)
#define SLABKK 72           // pair-rows in LDS (72 * 2KB = 144 KB); % 8 == 0
#define MM     (DIM / 4)    // 128 pair-pair steps
#define NSTR   ((MM - SLABKK / 2) / 4)   // 23 streamed steps per group
#define PFQ    6            // prefetched stream steps (12 uint4 = 48 VGPR)

typedef _Float16 h2_t __attribute__((ext_vector_type(2)));

#if defined(__has_builtin)
#  if __has_builtin(__builtin_amdgcn_fdot2)
#    define HAVE_FDOT2 1
#  endif
#endif
#ifndef HAVE_FDOT2
#  define HAVE_FDOT2 0
#endif

// acc += C_pair . p_pair (2 MACs, fp32 accumulate) — proven numerics
__device__ __forceinline__ float dot2acc(unsigned int cu, unsigned int pu, float acc) {
#if HAVE_FDOT2
    return __builtin_amdgcn_fdot2(__builtin_bit_cast(h2_t, cu),
                                  __builtin_bit_cast(h2_t, pu), acc, false);
#else
    const float2 cf = __half22float2(*reinterpret_cast<const __half2*>(&cu));
    const float2 pf = __half22float2(*reinterpret_cast<const __half2*>(&pu));
    return fmaf(cf.y, pf.y, fmaf(cf.x, pf.x, acc));
#endif
}

// ---------- 8-wave block sum (phase init only) ----------
__device__ __forceinline__ float block_reduce_sum(float v, float* red) {
    #pragma unroll
    for (int off = 32; off > 0; off >>= 1) v += __shfl_down(v, off, 64);
    const int wid = threadIdx.x >> 6, lane = threadIdx.x & 63;
    __syncthreads();
    if (lane == 0) red[wid] = v;
    __syncthreads();
    float s = 0.f;
    #pragma unroll
    for (int i = 0; i < 8; ++i) s += red[i];
    return s;
}

// ---------- fp32 matvec (refinement residual), proven ----------
__device__ __forceinline__ float matvec_assemble(float4 acc, float4* part, float4* w4_s) {
    const int tid = threadIdx.x;
    __syncthreads();
    part[tid] = acc;
    __syncthreads();
    if (tid < 128) {
        const float4 a0 = part[tid], a1 = part[tid + 128];
        const float4 a2 = part[tid + 256], a3 = part[tid + 384];
        float4 s4;
        s4.x = (a0.x + a1.x) + (a2.x + a3.x);
        s4.y = (a0.y + a1.y) + (a2.y + a3.y);
        s4.z = (a0.z + a1.z) + (a2.z + a3.z);
        s4.w = (a0.w + a1.w) + (a2.w + a3.w);
        w4_s[tid] = s4;
    }
    __syncthreads();
    return reinterpret_cast<const float*>(w4_s)[tid];
}

__device__ __forceinline__ float matvec32(const float4* __restrict__ Cq, const float* p_s,
                                          float4* part, float4* w4_s) {
    const int tid = threadIdx.x;
    const int g = tid >> 7, jq = tid & 127;
    float4 acc = make_float4(0.f, 0.f, 0.f, 0.f);
    int idx = g * 128 + jq;
    #pragma unroll 8
    for (int k = g; k < DIM; k += 4) {
        const float4 cv = Cq[idx];
        const float  pk = p_s[k];
        acc.x = fmaf(pk, cv.x, acc.x);
        acc.y = fmaf(pk, cv.y, acc.y);
        acc.z = fmaf(pk, cv.z, acc.z);
        acc.w = fmaf(pk, cv.w, acc.w);
        idx += 512;
    }
    return matvec_assemble(acc, part, w4_s);
}

// ---------- CG phase: fdot2 matvec, fp16 p, EXPLICIT residual, ----------
// ---------- + register prefetch of next-iter stream C (static addrs) ----------
__device__ float cg_phase(float bj, float a2, float s2,
                          const uint4* __restrict__ Cg, const uint4* C_lds,
                          float* p_s, unsigned short* p_h, float* w_s,
                          float4* part, float* red1, float* red2,
                          int maxit, float tolf)
{
    const int tid = threadIdx.x;
    const int g   = tid >> 7;
    const int jq  = tid & 127;
    const uint2* p_h64 = (const uint2*)p_h;

    float xj = 0.f, rj = bj, pj = bj;
    __syncthreads();                   // entry fence: prior readers of p_s/p_h done
    p_s[tid] = pj;
    p_h[tid] = __half_as_ushort(__float2half(pj));

    // prologue prefetch (C only — no p dependency; issues early, lands under init)
    uint4 pfa[PFQ], pfb[PFQ];
    #pragma unroll
    for (int q = 0; q < PFQ; ++q) {
        const int m = SLABKK / 2 + g + 4 * q;
        pfa[q] = Cg[(2 * m)     * 128 + jq];
        pfb[q] = Cg[(2 * m + 1) * 128 + jq];
    }

    float rs = block_reduce_sum(rj * rj, red2);   // internal barriers publish p
    if (!(rs > 0.f)) return xj;                   // uniform
    const float tol = tolf * rs;

    for (int it = 0; it < maxit; ++it) {
        float4 acc = make_float4(0.f, 0.f, 0.f, 0.f);
        {   // fresh streamed steps first (issue global loads ASAP)
            int m = SLABKK / 2 + g + 4 * PFQ;
            #pragma unroll
            for (int q = PFQ; q < NSTR; ++q, m += 4) {
                const uint4 cv0 = Cg[(2 * m)     * 128 + jq];
                const uint4 cv1 = Cg[(2 * m + 1) * 128 + jq];
                const uint2 pu  = p_h64[m];
                acc.x = dot2acc(cv1.x, pu.y, dot2acc(cv0.x, pu.x, acc.x));
                acc.y = dot2acc(cv1.y, pu.y, dot2acc(cv0.y, pu.x, acc.y));
                acc.z = dot2acc(cv1.z, pu.y, dot2acc(cv0.z, pu.x, acc.z));
                acc.w = dot2acc(cv1.w, pu.y, dot2acc(cv0.w, pu.x, acc.w));
            }
        }
        {   // LDS slab (fills time while globals are in flight)
            #pragma unroll
            for (int m = g; m < SLABKK / 2; m += 4) {
                const uint4 cv0 = C_lds[(2 * m)     * 128 + jq];
                const uint4 cv1 = C_lds[(2 * m + 1) * 128 + jq];
                const uint2 pu  = p_h64[m];
                acc.x = dot2acc(cv1.x, pu.y, dot2acc(cv0.x, pu.x, acc.x));
                acc.y = dot2acc(cv1.y, pu.y, dot2acc(cv0.y, pu.x, acc.y));
                acc.z = dot2acc(cv1.z, pu.y, dot2acc(cv0.z, pu.x, acc.z));
                acc.w = dot2acc(cv1.w, pu.y, dot2acc(cv0.w, pu.x, acc.w));
            }
        }
        {   // prefetched steps (registers already resident)
            #pragma unroll
            for (int q = 0; q < PFQ; ++q) {
                const int m = SLABKK / 2 + g + 4 * q;
                const uint2 pu = p_h64[m];
                acc.x = dot2acc(pfb[q].x, pu.y, dot2acc(pfa[q].x, pu.x, acc.x));
                acc.y = dot2acc(pfb[q].y, pu.y, dot2acc(pfa[q].y, pu.x, acc.y));
                acc.z = dot2acc(pfb[q].z, pu.y, dot2acc(pfa[q].z, pu.x, acc.z));
                acc.w = dot2acc(pfb[q].w, pu.y, dot2acc(pfa[q].w, pu.x, acc.w));
            }
        }
        part[tid] = acc;
        __syncthreads();                                   // A: part published

        // refill prefetch for NEXT iteration: keeps the memory pipe busy
        // through the assembly/reduction region (addresses are static).
        #pragma unroll
        for (int q = 0; q < PFQ; ++q) {
            const int m = SLABKK / 2 + g + 4 * q;
            pfa[q] = Cg[(2 * m)     * 128 + jq];
            pfb[q] = Cg[(2 * m + 1) * 128 + jq];
        }

        if (tid < 128) {
            const float4 a0 = part[tid],       a1 = part[tid + 128];
            const float4 b2 = part[tid + 256], a3 = part[tid + 384];
            float4 cw;
            cw.x = (a0.x + a1.x) + (b2.x + a3.x);
            cw.y = (a0.y + a1.y) + (b2.y + a3.y);
            cw.z = (a0.z + a1.z) + (b2.z + a3.z);
            cw.w = (a0.w + a1.w) + (b2.w + a3.w);
            const float4 p4 = reinterpret_cast<const float4*>(p_s)[tid];
            float4 w4;
            w4.x = fmaf(a2, cw.x, s2 * p4.x);
            w4.y = fmaf(a2, cw.y, s2 * p4.y);
            w4.z = fmaf(a2, cw.z, s2 * p4.z);
            w4.w = fmaf(a2, cw.w, s2 * p4.w);
            reinterpret_cast<float4*>(w_s)[tid] = w4;
            float pwp = p4.x*w4.x + p4.y*w4.y + p4.z*w4.z + p4.w*w4.w;
            #pragma unroll
            for (int off = 32; off > 0; off >>= 1) pwp += __shfl_down(pwp, off, 64);
            if ((tid & 63) == 0) red1[tid >> 6] = pwp;
        }
        __syncthreads();                                   // B: w_s + pw published
        const float pw    = fmaxf(red1[0] + red1[1], 1e-30f);
        const float alpha = rs / pw;
        const float wj    = w_s[tid];
        xj = fmaf( alpha, pj, xj);
        rj = fmaf(-alpha, wj, rj);
        {   // explicit ||r||^2 (robust to fp16-p matvec noise)
            float rr = rj * rj;
            #pragma unroll
            for (int off = 32; off > 0; off >>= 1) rr += __shfl_down(rr, off, 64);
            if ((tid & 63) == 0) red2[tid >> 6] = rr;
        }
        __syncthreads();                                   // C: r^2 partials
        float rsn = 0.f;
        #pragma unroll
        for (int i = 0; i < 8; ++i) rsn += red2[i];
        if (!(rsn > tol)) break;                           // uniform
        const float beta = rsn / rs;
        rs = rsn;
        pj = fmaf(beta, pj, rj);
        p_s[tid] = pj;
        p_h[tid] = __half_as_ushort(__float2half(pj));
        __syncthreads();                                   // D: p published
    }
    return xj;
}

// ---------- main solver: one block per item ----------
__global__ __launch_bounds__(NTHR, 1)
void vps_solve_kernel(const float* __restrict__ t_arr,
                      const float* __restrict__ x_arr,
                      const float* __restrict__ mean0,
                      const float* __restrict__ cov0,
                      const uint4* __restrict__ Cp,
                      float* __restrict__ out)
{
    __shared__ uint4  C_lds[SLABKK * 128];                 // 144 KB slab
    __shared__ float4 part[NTHR];                          // 8 KB
    __shared__ float4 p4_s[DIM / 4];                       // 2 KB
    __shared__ float4 w4_s[DIM / 4];                       // 2 KB
    __shared__ __align__(8) unsigned short p_h[DIM];       // 1 KB
    __shared__ float  red1[8];
    __shared__ float  red2[8];
    float* p_s = (float*)p4_s;
    float* w_s = (float*)w4_s;

    const int b   = blockIdx.x;
    const int tid = threadIdx.x;

    const float t  = t_arr[b];
    const float ib = 0.1f * t + 9.95f * t * t;
    const float a  = expf(-0.5f * ib);
    const float a2 = a * a;
    const float s2 = fmaxf(1.0f - a2, 1e-12f);

    const float rhs = x_arr[b * DIM + tid] - a * mean0[tid];

    // load slab once (coalesced uint4; 18 per thread)
    for (int i = tid; i < SLABKK * 128; i += NTHR) C_lds[i] = Cp[i];
    // cg_phase's entry barriers make the slab visible before the first matvec.

    // Phase 1: CG on fp16 pair-packed matrix (rel-r ~2.8e-2)
    const float x1 = cg_phase(rhs, a2, s2, Cp, C_lds, p_s, p_h, w_s, part,
                              red1, red2, 20, 8e-4f);

    // Exact fp32 residual
    __syncthreads();
    p_s[tid] = x1;
    __syncthreads();
    const float cw  = matvec32(reinterpret_cast<const float4*>(cov0), p_s, part, w4_s);
    const float rtj = rhs - (a2 * cw + s2 * x1);

    // Phase 2: correction solve (absorbs fp16 matrix + fp16-p perturbation)
    const float z = cg_phase(rtj, a2, s2, Cp, C_lds, p_s, p_h, w_s, part,
                             red1, red2, 18, 1.8e-3f);

    out[b * DIM + tid] = -(x1 + z);
}

// ---------- pack cov0 -> pair-interleaved fp16 (proven) ----------
__global__ void conv_pack_kernel(const float* __restrict__ C, unsigned int* __restrict__ out) {
    const int id = blockIdx.x * 256 + threadIdx.x;   // 131072 total
    const int kk = id >> 9;
    const int j  = id & 511;
    const __half2 h = __floats2half2_rn(C[(2 * kk) * DIM + j], C[(2 * kk + 1) * DIM + j]);
    out[id] = *reinterpret_cast<const unsigned int*>(&h);
}

// ================= fallback path (ws too small): proven fp32 CG =================
__global__ __launch_bounds__(NTHR, 1)
void vps_cg_kernel(const float* __restrict__ t_arr, const float* __restrict__ x_arr,
                   const float* __restrict__ mean0, const float* __restrict__ cov0,
                   float* __restrict__ out)
{
    const int b = blockIdx.x, tid = threadIdx.x;
    __shared__ float4 part[NTHR];
    __shared__ float4 p4_s[DIM / 4];
    __shared__ float4 w4_s[DIM / 4];
    __shared__ float  red[16];
    float* p_s = (float*)p4_s;
    const float t  = t_arr[b];
    const float ib = 0.1f * t + 9.95f * t * t;
    const float a  = expf(-0.5f * ib);
    const float a2 = a * a;
    const float s2 = fmaxf(1.0f - a2, 1e-12f);
    const float rhs = x_arr[b * DIM + tid] - a * mean0[tid];
    float xj = 0.f, rj = rhs, pj = rhs;
    p_s[tid] = pj;
    float rs = block_reduce_sum(rj * rj, red);
    const float tol = rs * 1e-12f;
    for (int it = 0; it < 72; ++it) {
        const float cw = matvec32(reinterpret_cast<const float4*>(cov0), p_s, part, w4_s);
        const float wj = a2 * cw + s2 * pj;
        const float pw = block_reduce_sum(pj * wj, red);
        const float alpha = rs / fmaxf(pw, 1e-37f);
        xj = fmaf(alpha, pj, xj);
        rj = fmaf(-alpha, wj, rj);
        const float rsn = block_reduce_sum(rj * rj, red);
        if (rsn < tol) break;
        const float beta = rsn / fmaxf(rs, 1e-37f);
        pj = fmaf(beta, pj, rj);
        rs = rsn;
        p_s[tid] = pj;
        __syncthreads();
    }
    out[b * DIM + tid] = -xj;
}

extern "C" void kernel_launch(void* const* d_in, const int* in_sizes, int n_in,
                              void* d_out, int out_size, void* d_ws, size_t ws_size,
                              hipStream_t stream) {
    const float* t_arr = (const float*)d_in[0];
    const float* x_arr = (const float*)d_in[1];
    const float* m0    = (const float*)d_in[2];
    const float* c0    = (const float*)d_in[3];
    float* out = (float*)d_out;
    const int B = in_sizes[0];   // 128
    const size_t need = (size_t)NKK * DIM * 4;   // 512 KB packed fp16
    if (ws_size >= need) {
        hipLaunchKernelGGL(conv_pack_kernel, dim3(NKK * DIM / 256), dim3(256), 0, stream,
                           c0, (unsigned int*)d_ws);
        hipLaunchKernelGGL(vps_solve_kernel, dim3(B), dim3(NTHR), 0, stream,
                           t_arr, x_arr, m0, c0, (const uint4*)d_ws, out);
    } else {
        hipLaunchKernelGGL(vps_cg_kernel, dim3(B), dim3(NTHR), 0, stream,
                           t_arr, x_arr, m0, c0, out);
    }
}

// Round 9
// 140.016 us; speedup vs baseline: 2.7987x; 2.7987x over previous
//
#include <hip/hip_runtime.h>
#include <hip/hip_fp16.h>
#include <math.h>

#define DIM    512
#define NTHR   512
#define NKK    256          // pair-rows (2 matrix rows per pair)
#define SLABKK 72           // pair-rows in LDS (72 * 2KB = 144 KB); % 8 == 0
#define MM     (DIM / 4)    // 128 pair-pair steps

typedef _Float16 h2_t __attribute__((ext_vector_type(2)));

#if defined(__has_builtin)
#  if __has_builtin(__builtin_amdgcn_fdot2)
#    define HAVE_FDOT2 1
#  endif
#endif
#ifndef HAVE_FDOT2
#  define HAVE_FDOT2 0
#endif

// acc += C_pair . p_pair (2 MACs, fp32 accumulate) — proven numerics
__device__ __forceinline__ float dot2acc(unsigned int cu, unsigned int pu, float acc) {
#if HAVE_FDOT2
    return __builtin_amdgcn_fdot2(__builtin_bit_cast(h2_t, cu),
                                  __builtin_bit_cast(h2_t, pu), acc, false);
#else
    const float2 cf = __half22float2(*reinterpret_cast<const __half2*>(&cu));
    const float2 pf = __half22float2(*reinterpret_cast<const __half2*>(&pu));
    return fmaf(cf.y, pf.y, fmaf(cf.x, pf.x, acc));
#endif
}

// ---------- 8-wave block sum (phase init only) ----------
__device__ __forceinline__ float block_reduce_sum(float v, float* red) {
    #pragma unroll
    for (int off = 32; off > 0; off >>= 1) v += __shfl_down(v, off, 64);
    const int wid = threadIdx.x >> 6, lane = threadIdx.x & 63;
    __syncthreads();
    if (lane == 0) red[wid] = v;
    __syncthreads();
    float s = 0.f;
    #pragma unroll
    for (int i = 0; i < 8; ++i) s += red[i];
    return s;
}

// ---------- fp32 matvec (refinement residual), proven ----------
__device__ __forceinline__ float matvec_assemble(float4 acc, float4* part, float4* w4_s) {
    const int tid = threadIdx.x;
    __syncthreads();
    part[tid] = acc;
    __syncthreads();
    if (tid < 128) {
        const float4 a0 = part[tid], a1 = part[tid + 128];
        const float4 a2 = part[tid + 256], a3 = part[tid + 384];
        float4 s4;
        s4.x = (a0.x + a1.x) + (a2.x + a3.x);
        s4.y = (a0.y + a1.y) + (a2.y + a3.y);
        s4.z = (a0.z + a1.z) + (a2.z + a3.z);
        s4.w = (a0.w + a1.w) + (a2.w + a3.w);
        w4_s[tid] = s4;
    }
    __syncthreads();
    return reinterpret_cast<const float*>(w4_s)[tid];
}

__device__ __forceinline__ float matvec32(const float4* __restrict__ Cq, const float* p_s,
                                          float4* part, float4* w4_s) {
    const int tid = threadIdx.x;
    const int g = tid >> 7, jq = tid & 127;
    float4 acc = make_float4(0.f, 0.f, 0.f, 0.f);
    int idx = g * 128 + jq;
    #pragma unroll 8
    for (int k = g; k < DIM; k += 4) {
        const float4 cv = Cq[idx];
        const float  pk = p_s[k];
        acc.x = fmaf(pk, cv.x, acc.x);
        acc.y = fmaf(pk, cv.y, acc.y);
        acc.z = fmaf(pk, cv.z, acc.z);
        acc.w = fmaf(pk, cv.w, acc.w);
        idx += 512;
    }
    return matvec_assemble(acc, part, w4_s);
}

// ---------- pair-packed fdot2 matvec body (b64 p-broadcasts) ----------
// Cp layout: uint at [kk*DIM + j] = half2(C[2kk][j], C[2kk+1][j]);
// quad (uint4) index [kk*128 + jq] = cols 4jq..4jq+3 of pair-row kk.
// Pair-pair step m covers pair-rows 2m, 2m+1 (k = 4m..4m+3); thread group
// g handles m ≡ g (mod 4); p read once per step as uint2 (b64 broadcast).
__device__ __forceinline__ float4 matvec16_body(const uint4* __restrict__ Cg,
                                                const uint4* C_lds,
                                                const uint2* p_h64,
                                                int g, int jq) {
    float4 acc = make_float4(0.f, 0.f, 0.f, 0.f);
    #pragma unroll
    for (int m = g; m < SLABKK / 2; m += 4) {        // 9 steps from LDS slab
        const uint4 cv0 = C_lds[(2 * m)     * 128 + jq];
        const uint4 cv1 = C_lds[(2 * m + 1) * 128 + jq];
        const uint2 pu  = p_h64[m];                  // wave-uniform b64 broadcast
        acc.x = dot2acc(cv1.x, pu.y, dot2acc(cv0.x, pu.x, acc.x));
        acc.y = dot2acc(cv1.y, pu.y, dot2acc(cv0.y, pu.x, acc.y));
        acc.z = dot2acc(cv1.z, pu.y, dot2acc(cv0.z, pu.x, acc.z));
        acc.w = dot2acc(cv1.w, pu.y, dot2acc(cv0.w, pu.x, acc.w));
    }
    #pragma unroll
    for (int m = SLABKK / 2 + g; m < MM; m += 4) {   // 23 steps from L2, 32B/lane
        const uint4 cv0 = Cg[(2 * m)     * 128 + jq];
        const uint4 cv1 = Cg[(2 * m + 1) * 128 + jq];
        const uint2 pu  = p_h64[m];
        acc.x = dot2acc(cv1.x, pu.y, dot2acc(cv0.x, pu.x, acc.x));
        acc.y = dot2acc(cv1.y, pu.y, dot2acc(cv0.y, pu.x, acc.y));
        acc.z = dot2acc(cv1.z, pu.y, dot2acc(cv0.z, pu.x, acc.z));
        acc.w = dot2acc(cv1.w, pu.y, dot2acc(cv0.w, pu.x, acc.w));
    }
    return acc;
}

// ---------- CG phase: fdot2 matvec, fp16 p, EXPLICIT residual, 4 barriers/iter ----------
__device__ float cg_phase(float bj, float a2, float s2,
                          const uint4* __restrict__ Cg, const uint4* C_lds,
                          float* p_s, unsigned short* p_h, float* w_s,
                          float4* part, float* red1, float* red2,
                          int maxit, float tolf)
{
    const int tid = threadIdx.x;
    const int g   = tid >> 7;
    const int jq  = tid & 127;
    const uint2* p_h64 = (const uint2*)p_h;

    float xj = 0.f, rj = bj, pj = bj;
    __syncthreads();                   // entry fence: prior readers of p_s/p_h done
    p_s[tid] = pj;
    p_h[tid] = __half_as_ushort(__float2half(pj));
    float rs = block_reduce_sum(rj * rj, red2);   // internal barriers publish p
    if (!(rs > 0.f)) return xj;                   // uniform
    const float tol = tolf * rs;

    for (int it = 0; it < maxit; ++it) {
        const float4 acc = matvec16_body(Cg, C_lds, p_h64, g, jq);
        part[tid] = acc;
        __syncthreads();                                   // A: part published
        if (tid < 128) {
            const float4 a0 = part[tid],       a1 = part[tid + 128];
            const float4 b2 = part[tid + 256], a3 = part[tid + 384];
            float4 cw;
            cw.x = (a0.x + a1.x) + (b2.x + a3.x);
            cw.y = (a0.y + a1.y) + (b2.y + a3.y);
            cw.z = (a0.z + a1.z) + (b2.z + a3.z);
            cw.w = (a0.w + a1.w) + (b2.w + a3.w);
            const float4 p4 = reinterpret_cast<const float4*>(p_s)[tid];
            float4 w4;
            w4.x = fmaf(a2, cw.x, s2 * p4.x);
            w4.y = fmaf(a2, cw.y, s2 * p4.y);
            w4.z = fmaf(a2, cw.z, s2 * p4.z);
            w4.w = fmaf(a2, cw.w, s2 * p4.w);
            reinterpret_cast<float4*>(w_s)[tid] = w4;
            float pwp = p4.x*w4.x + p4.y*w4.y + p4.z*w4.z + p4.w*w4.w;
            #pragma unroll
            for (int off = 32; off > 0; off >>= 1) pwp += __shfl_down(pwp, off, 64);
            if ((tid & 63) == 0) red1[tid >> 6] = pwp;
        }
        __syncthreads();                                   // B: w_s + pw published
        const float pw    = fmaxf(red1[0] + red1[1], 1e-30f);
        const float alpha = rs / pw;
        const float wj    = w_s[tid];
        xj = fmaf( alpha, pj, xj);
        rj = fmaf(-alpha, wj, rj);
        {   // explicit ||r||^2 (robust to fp16-p matvec noise)
            float rr = rj * rj;
            #pragma unroll
            for (int off = 32; off > 0; off >>= 1) rr += __shfl_down(rr, off, 64);
            if ((tid & 63) == 0) red2[tid >> 6] = rr;
        }
        __syncthreads();                                   // C: r^2 partials
        float rsn = 0.f;
        #pragma unroll
        for (int i = 0; i < 8; ++i) rsn += red2[i];
        if (!(rsn > tol)) break;                           // uniform
        const float beta = rsn / rs;
        rs = rsn;
        pj = fmaf(beta, pj, rj);
        p_s[tid] = pj;
        p_h[tid] = __half_as_ushort(__float2half(pj));
        __syncthreads();                                   // D: p published
    }
    return xj;
}

// ---------- main solver: one block per item ----------
__global__ __launch_bounds__(NTHR, 1)
void vps_solve_kernel(const float* __restrict__ t_arr,
                      const float* __restrict__ x_arr,
                      const float* __restrict__ mean0,
                      const float* __restrict__ cov0,
                      const uint4* __restrict__ Cp,
                      float* __restrict__ out)
{
    __shared__ uint4  C_lds[SLABKK * 128];                 // 144 KB slab
    __shared__ float4 part[NTHR];                          // 8 KB
    __shared__ float4 p4_s[DIM / 4];                       // 2 KB
    __shared__ float4 w4_s[DIM / 4];                       // 2 KB
    __shared__ __align__(8) unsigned short p_h[DIM];       // 1 KB
    __shared__ float  red1[8];
    __shared__ float  red2[8];
    float* p_s = (float*)p4_s;
    float* w_s = (float*)w4_s;

    const int b   = blockIdx.x;
    const int tid = threadIdx.x;

    const float t  = t_arr[b];
    const float ib = 0.1f * t + 9.95f * t * t;
    const float a  = expf(-0.5f * ib);
    const float a2 = a * a;
    const float s2 = fmaxf(1.0f - a2, 1e-12f);

    const float rhs = x_arr[b * DIM + tid] - a * mean0[tid];

    // load slab once (coalesced uint4; 18 per thread)
    for (int i = tid; i < SLABKK * 128; i += NTHR) C_lds[i] = Cp[i];
    // cg_phase's entry barriers make the slab visible before the first matvec.

    // Phase 1: CG on fp16 pair-packed matrix (rel-r ~2.8e-2)
    const float x1 = cg_phase(rhs, a2, s2, Cp, C_lds, p_s, p_h, w_s, part,
                              red1, red2, 20, 8e-4f);

    // Exact fp32 residual
    __syncthreads();
    p_s[tid] = x1;
    __syncthreads();
    const float cw  = matvec32(reinterpret_cast<const float4*>(cov0), p_s, part, w4_s);
    const float rtj = rhs - (a2 * cw + s2 * x1);

    // Phase 2: correction solve (absorbs fp16 matrix + fp16-p perturbation)
    const float z = cg_phase(rtj, a2, s2, Cp, C_lds, p_s, p_h, w_s, part,
                             red1, red2, 18, 1.8e-3f);

    out[b * DIM + tid] = -(x1 + z);
}

// ---------- pack cov0 -> pair-interleaved fp16 (proven) ----------
__global__ void conv_pack_kernel(const float* __restrict__ C, unsigned int* __restrict__ out) {
    const int id = blockIdx.x * 256 + threadIdx.x;   // 131072 total
    const int kk = id >> 9;
    const int j  = id & 511;
    const __half2 h = __floats2half2_rn(C[(2 * kk) * DIM + j], C[(2 * kk + 1) * DIM + j]);
    out[id] = *reinterpret_cast<const unsigned int*>(&h);
}

// ================= fallback path (ws too small): proven fp32 CG =================
__global__ __launch_bounds__(NTHR, 1)
void vps_cg_kernel(const float* __restrict__ t_arr, const float* __restrict__ x_arr,
                   const float* __restrict__ mean0, const float* __restrict__ cov0,
                   float* __restrict__ out)
{
    const int b = blockIdx.x, tid = threadIdx.x;
    __shared__ float4 part[NTHR];
    __shared__ float4 p4_s[DIM / 4];
    __shared__ float4 w4_s[DIM / 4];
    __shared__ float  red[16];
    float* p_s = (float*)p4_s;
    const float t  = t_arr[b];
    const float ib = 0.1f * t + 9.95f * t * t;
    const float a  = expf(-0.5f * ib);
    const float a2 = a * a;
    const float s2 = fmaxf(1.0f - a2, 1e-12f);
    const float rhs = x_arr[b * DIM + tid] - a * mean0[tid];
    float xj = 0.f, rj = rhs, pj = rhs;
    p_s[tid] = pj;
    float rs = block_reduce_sum(rj * rj, red);
    const float tol = rs * 1e-12f;
    for (int it = 0; it < 72; ++it) {
        const float cw = matvec32(reinterpret_cast<const float4*>(cov0), p_s, part, w4_s);
        const float wj = a2 * cw + s2 * pj;
        const float pw = block_reduce_sum(pj * wj, red);
        const float alpha = rs / fmaxf(pw, 1e-37f);
        xj = fmaf(alpha, pj, xj);
        rj = fmaf(-alpha, wj, rj);
        const float rsn = block_reduce_sum(rj * rj, red);
        if (rsn < tol) break;
        const float beta = rsn / fmaxf(rs, 1e-37f);
        pj = fmaf(beta, pj, rj);
        rs = rsn;
        p_s[tid] = pj;
        __syncthreads();
    }
    out[b * DIM + tid] = -xj;
}

extern "C" void kernel_launch(void* const* d_in, const int* in_sizes, int n_in,
                              void* d_out, int out_size, void* d_ws, size_t ws_size,
                              hipStream_t stream) {
    const float* t_arr = (const float*)d_in[0];
    const float* x_arr = (const float*)d_in[1];
    const float* m0    = (const float*)d_in[2];
    const float* c0    = (const float*)d_in[3];
    float* out = (float*)d_out;
    const int B = in_sizes[0];   // 128
    const size_t need = (size_t)NKK * DIM * 4;   // 512 KB packed fp16
    if (ws_size >= need) {
        hipLaunchKernelGGL(conv_pack_kernel, dim3(NKK * DIM / 256), dim3(256), 0, stream,
                           c0, (unsigned int*)d_ws);
        hipLaunchKernelGGL(vps_solve_kernel, dim3(B), dim3(NTHR), 0, stream,
                           t_arr, x_arr, m0, c0, (const uint4*)d_ws, out);
    } else {
        hipLaunchKernelGGL(vps_cg_kernel, dim3(B), dim3(NTHR), 0, stream,
                           t_arr, x_arr, m0, c0, out);
    }
}

// Round 10
// 137.702 us; speedup vs baseline: 2.8458x; 1.0168x over previous
//
#include <hip/hip_runtime.h>
#include <hip/hip_fp16.h>
#include <math.h>

#define DIM    512
#define NTHR   512
#define NKK    256          // pair-rows (2 matrix rows per pair)
#define SLABKK 72           // pair-rows in LDS (72 * 2KB = 144 KB); % 8 == 0
#define MM     (DIM / 4)    // 128 pair-pair steps

typedef _Float16 h2_t __attribute__((ext_vector_type(2)));

#if defined(__has_builtin)
#  if __has_builtin(__builtin_amdgcn_fdot2)
#    define HAVE_FDOT2 1
#  endif
#endif
#ifndef HAVE_FDOT2
#  define HAVE_FDOT2 0
#endif

// acc += C_pair . p_pair (2 MACs, fp32 accumulate) — proven numerics
__device__ __forceinline__ float dot2acc(unsigned int cu, unsigned int pu, float acc) {
#if HAVE_FDOT2
    return __builtin_amdgcn_fdot2(__builtin_bit_cast(h2_t, cu),
                                  __builtin_bit_cast(h2_t, pu), acc, false);
#else
    const float2 cf = __half22float2(*reinterpret_cast<const __half2*>(&cu));
    const float2 pf = __half22float2(*reinterpret_cast<const __half2*>(&pu));
    return fmaf(cf.y, pf.y, fmaf(cf.x, pf.x, acc));
#endif
}

// ---------- 8-wave block sum (phase init only) ----------
__device__ __forceinline__ float block_reduce_sum(float v, float* red) {
    #pragma unroll
    for (int off = 32; off > 0; off >>= 1) v += __shfl_down(v, off, 64);
    const int wid = threadIdx.x >> 6, lane = threadIdx.x & 63;
    __syncthreads();
    if (lane == 0) red[wid] = v;
    __syncthreads();
    float s = 0.f;
    #pragma unroll
    for (int i = 0; i < 8; ++i) s += red[i];
    return s;
}

// ---------- fp32 matvec (refinement residual), proven ----------
__device__ __forceinline__ float matvec_assemble(float4 acc, float4* part, float4* w4_s) {
    const int tid = threadIdx.x;
    __syncthreads();
    part[tid] = acc;
    __syncthreads();
    if (tid < 128) {
        const float4 a0 = part[tid], a1 = part[tid + 128];
        const float4 a2 = part[tid + 256], a3 = part[tid + 384];
        float4 s4;
        s4.x = (a0.x + a1.x) + (a2.x + a3.x);
        s4.y = (a0.y + a1.y) + (a2.y + a3.y);
        s4.z = (a0.z + a1.z) + (a2.z + a3.z);
        s4.w = (a0.w + a1.w) + (a2.w + a3.w);
        w4_s[tid] = s4;
    }
    __syncthreads();
    return reinterpret_cast<const float*>(w4_s)[tid];
}

__device__ __forceinline__ float matvec32(const float4* __restrict__ Cq, const float* p_s,
                                          float4* part, float4* w4_s) {
    const int tid = threadIdx.x;
    const int g = tid >> 7, jq = tid & 127;
    float4 acc = make_float4(0.f, 0.f, 0.f, 0.f);
    int idx = g * 128 + jq;
    #pragma unroll 8
    for (int k = g; k < DIM; k += 4) {
        const float4 cv = Cq[idx];
        const float  pk = p_s[k];
        acc.x = fmaf(pk, cv.x, acc.x);
        acc.y = fmaf(pk, cv.y, acc.y);
        acc.z = fmaf(pk, cv.z, acc.z);
        acc.w = fmaf(pk, cv.w, acc.w);
        idx += 512;
    }
    return matvec_assemble(acc, part, w4_s);
}

// ---------- pair-packed fdot2 matvec body (b64 p-broadcasts), proven ----------
__device__ __forceinline__ float4 matvec16_body(const uint4* __restrict__ Cg,
                                                const uint4* C_lds,
                                                const uint2* p_h64,
                                                int g, int jq) {
    float4 acc = make_float4(0.f, 0.f, 0.f, 0.f);
    #pragma unroll
    for (int m = g; m < SLABKK / 2; m += 4) {        // 9 steps from LDS slab
        const uint4 cv0 = C_lds[(2 * m)     * 128 + jq];
        const uint4 cv1 = C_lds[(2 * m + 1) * 128 + jq];
        const uint2 pu  = p_h64[m];                  // wave-uniform b64 broadcast
        acc.x = dot2acc(cv1.x, pu.y, dot2acc(cv0.x, pu.x, acc.x));
        acc.y = dot2acc(cv1.y, pu.y, dot2acc(cv0.y, pu.x, acc.y));
        acc.z = dot2acc(cv1.z, pu.y, dot2acc(cv0.z, pu.x, acc.z));
        acc.w = dot2acc(cv1.w, pu.y, dot2acc(cv0.w, pu.x, acc.w));
    }
    #pragma unroll
    for (int m = SLABKK / 2 + g; m < MM; m += 4) {   // 23 steps from L2, 32B/lane
        const uint4 cv0 = Cg[(2 * m)     * 128 + jq];
        const uint4 cv1 = Cg[(2 * m + 1) * 128 + jq];
        const uint2 pu  = p_h64[m];
        acc.x = dot2acc(cv1.x, pu.y, dot2acc(cv0.x, pu.x, acc.x));
        acc.y = dot2acc(cv1.y, pu.y, dot2acc(cv0.y, pu.x, acc.y));
        acc.z = dot2acc(cv1.z, pu.y, dot2acc(cv0.z, pu.x, acc.z));
        acc.w = dot2acc(cv1.w, pu.y, dot2acc(cv0.w, pu.x, acc.w));
    }
    return acc;
}

// ---------- CG phase: fdot2 matvec, fp16 p, 3 barriers/iter ----------
// Single merged reduction (p.w, r.w, w.w); rsn = ||r - a w||^2 expanded
// analytically — exact algebra, no CG identities, robust to fp16-p.
__device__ float cg_phase(float bj, float a2, float s2,
                          const uint4* __restrict__ Cg, const uint4* C_lds,
                          unsigned short* p_h, float4* part, float* red,
                          int maxit, float tolf)
{
    const int tid = threadIdx.x;
    const int g   = tid >> 7;
    const int jq  = tid & 127;
    const uint2* p_h64 = (const uint2*)p_h;
    const float* partf = (const float*)part;

    float xj = 0.f, rj = bj, pj = bj;
    __syncthreads();                   // entry fence: prior readers of p_h/part done
    p_h[tid] = __half_as_ushort(__float2half(pj));
    float rs = block_reduce_sum(rj * rj, red);    // internal barriers publish p_h
    if (!(rs > 0.f)) return xj;                   // uniform
    const float tol = tolf * rs;

    for (int it = 0; it < maxit; ++it) {
        const float4 acc = matvec16_body(Cg, C_lds, p_h64, g, jq);
        part[tid] = acc;
        __syncthreads();                                   // A: part published

        // self-assembly: w[tid] = sum over 4 groups (2-way bank alias = free)
        const float cw = partf[tid] + partf[512 + tid]
                       + partf[1024 + tid] + partf[1536 + tid];
        const float wj = fmaf(a2, cw, s2 * pj);

        // merged 3-dot partials
        float pwp = pj * wj, rwp = rj * wj, wwp = wj * wj;
        #pragma unroll
        for (int off = 32; off > 0; off >>= 1) {
            pwp += __shfl_down(pwp, off, 64);
            rwp += __shfl_down(rwp, off, 64);
            wwp += __shfl_down(wwp, off, 64);
        }
        if ((tid & 63) == 0) {
            const int w4 = (tid >> 6) * 4;
            red[w4] = pwp; red[w4 + 1] = rwp; red[w4 + 2] = wwp;
        }
        __syncthreads();                                   // B: partials published
        float pw = 0.f, rw = 0.f, ww = 0.f;
        #pragma unroll
        for (int w = 0; w < 8; ++w) {                      // uniform broadcast reads
            pw += red[w * 4]; rw += red[w * 4 + 1]; ww += red[w * 4 + 2];
        }
        pw = fmaxf(pw, 1e-30f);
        const float alpha = rs / pw;
        xj = fmaf( alpha, pj, xj);
        rj = fmaf(-alpha, wj, rj);
        // rsn = ||r_old - alpha w||^2 = rs - 2 a rw + a^2 ww  (exact expansion)
        const float rsn = fmaf(alpha * alpha, ww, fmaf(-2.0f * alpha, rw, rs));
        if (!(rsn > tol)) break;                           // uniform; NaN/neg safe
        const float beta = rsn / rs;
        rs = rsn;
        pj = fmaf(beta, pj, rj);
        p_h[tid] = __half_as_ushort(__float2half(pj));
        __syncthreads();                                   // D: p published
    }
    return xj;
}

// ---------- main solver: one block per item ----------
__global__ __launch_bounds__(NTHR, 1)
void vps_solve_kernel(const float* __restrict__ t_arr,
                      const float* __restrict__ x_arr,
                      const float* __restrict__ mean0,
                      const float* __restrict__ cov0,
                      const uint4* __restrict__ Cp,
                      float* __restrict__ out)
{
    __shared__ uint4  C_lds[SLABKK * 128];                 // 144 KB slab
    __shared__ float4 part[NTHR];                          // 8 KB
    __shared__ float4 p4_s[DIM / 4];                       // 2 KB (refinement p)
    __shared__ float4 w4_s[DIM / 4];                       // 2 KB (refinement w)
    __shared__ __align__(8) unsigned short p_h[DIM];       // 1 KB
    __shared__ float  red[32];
    float* p_s = (float*)p4_s;

    const int b   = blockIdx.x;
    const int tid = threadIdx.x;

    const float t  = t_arr[b];
    const float ib = 0.1f * t + 9.95f * t * t;
    const float a  = expf(-0.5f * ib);
    const float a2 = a * a;
    const float s2 = fmaxf(1.0f - a2, 1e-12f);

    const float rhs = x_arr[b * DIM + tid] - a * mean0[tid];

    // load slab once (coalesced uint4; 18 per thread)
    for (int i = tid; i < SLABKK * 128; i += NTHR) C_lds[i] = Cp[i];
    // cg_phase's entry barriers make the slab visible before the first matvec.

    // Phase 1: CG on fp16 pair-packed matrix (rel-r ~3.9e-2)
    const float x1 = cg_phase(rhs, a2, s2, Cp, C_lds, p_h, part, red, 20, 1.5e-3f);

    // Exact fp32 residual
    __syncthreads();
    p_s[tid] = x1;
    __syncthreads();
    const float cw  = matvec32(reinterpret_cast<const float4*>(cov0), p_s, part, w4_s);
    const float rtj = rhs - (a2 * cw + s2 * x1);

    // Phase 2: correction solve (absorbs fp16 matrix + fp16-p perturbation)
    const float z = cg_phase(rtj, a2, s2, Cp, C_lds, p_h, part, red, 18, 3.5e-3f);

    out[b * DIM + tid] = -(x1 + z);
}

// ---------- pack cov0 -> pair-interleaved fp16 (proven) ----------
__global__ void conv_pack_kernel(const float* __restrict__ C, unsigned int* __restrict__ out) {
    const int id = blockIdx.x * 256 + threadIdx.x;   // 131072 total
    const int kk = id >> 9;
    const int j  = id & 511;
    const __half2 h = __floats2half2_rn(C[(2 * kk) * DIM + j], C[(2 * kk + 1) * DIM + j]);
    out[id] = *reinterpret_cast<const unsigned int*>(&h);
}

// ================= fallback path (ws too small): proven fp32 CG =================
__global__ __launch_bounds__(NTHR, 1)
void vps_cg_kernel(const float* __restrict__ t_arr, const float* __restrict__ x_arr,
                   const float* __restrict__ mean0, const float* __restrict__ cov0,
                   float* __restrict__ out)
{
    const int b = blockIdx.x, tid = threadIdx.x;
    __shared__ float4 part[NTHR];
    __shared__ float4 p4_s[DIM / 4];
    __shared__ float4 w4_s[DIM / 4];
    __shared__ float  red[16];
    float* p_s = (float*)p4_s;
    const float t  = t_arr[b];
    const float ib = 0.1f * t + 9.95f * t * t;
    const float a  = expf(-0.5f * ib);
    const float a2 = a * a;
    const float s2 = fmaxf(1.0f - a2, 1e-12f);
    const float rhs = x_arr[b * DIM + tid] - a * mean0[tid];
    float xj = 0.f, rj = rhs, pj = rhs;
    p_s[tid] = pj;
    float rs = block_reduce_sum(rj * rj, red);
    const float tol = rs * 1e-12f;
    for (int it = 0; it < 72; ++it) {
        const float cw = matvec32(reinterpret_cast<const float4*>(cov0), p_s, part, w4_s);
        const float wj = a2 * cw + s2 * pj;
        const float pw = block_reduce_sum(pj * wj, red);
        const float alpha = rs / fmaxf(pw, 1e-37f);
        xj = fmaf(alpha, pj, xj);
        rj = fmaf(-alpha, wj, rj);
        const float rsn = block_reduce_sum(rj * rj, red);
        if (rsn < tol) break;
        const float beta = rsn / fmaxf(rs, 1e-37f);
        pj = fmaf(beta, pj, rj);
        rs = rsn;
        p_s[tid] = pj;
        __syncthreads();
    }
    out[b * DIM + tid] = -xj;
}

extern "C" void kernel_launch(void* const* d_in, const int* in_sizes, int n_in,
                              void* d_out, int out_size, void* d_ws, size_t ws_size,
                              hipStream_t stream) {
    const float* t_arr = (const float*)d_in[0];
    const float* x_arr = (const float*)d_in[1];
    const float* m0    = (const float*)d_in[2];
    const float* c0    = (const float*)d_in[3];
    float* out = (float*)d_out;
    const int B = in_sizes[0];   // 128
    const size_t need = (size_t)NKK * DIM * 4;   // 512 KB packed fp16
    if (ws_size >= need) {
        hipLaunchKernelGGL(conv_pack_kernel, dim3(NKK * DIM / 256), dim3(256), 0, stream,
                           c0, (unsigned int*)d_ws);
        hipLaunchKernelGGL(vps_solve_kernel, dim3(B), dim3(NTHR), 0, stream,
                           t_arr, x_arr, m0, c0, (const uint4*)d_ws, out);
    } else {
        hipLaunchKernelGGL(vps_cg_kernel, dim3(B), dim3(NTHR), 0, stream,
                           t_arr, x_arr, m0, c0, out);
    }
}

// Round 11
// 122.412 us; speedup vs baseline: 3.2012x; 1.1249x over previous
//
#include <hip/hip_runtime.h>
#include <hip/hip_fp16.h>
#include <math.h>

#define DIM    512
#define NTHR   512
#define NKK    256          // pair-rows (2 matrix rows per pair)
#define SLABKK 72           // pair-rows in LDS (72 * 2KB = 144 KB); % 8 == 0
#define MM     (DIM / 4)    // 128 pair-pair steps
#define S2     (SLABKK / 2) // 36: first streamed pair-pair step

typedef _Float16 h2_t __attribute__((ext_vector_type(2)));

#if defined(__has_builtin)
#  if __has_builtin(__builtin_amdgcn_fdot2)
#    define HAVE_FDOT2 1
#  endif
#endif
#ifndef HAVE_FDOT2
#  define HAVE_FDOT2 0
#endif

// acc += C_pair . p_pair (2 MACs, fp32 accumulate) — proven numerics
__device__ __forceinline__ float dot2acc(unsigned int cu, unsigned int pu, float acc) {
#if HAVE_FDOT2
    return __builtin_amdgcn_fdot2(__builtin_bit_cast(h2_t, cu),
                                  __builtin_bit_cast(h2_t, pu), acc, false);
#else
    const float2 cf = __half22float2(*reinterpret_cast<const __half2*>(&cu));
    const float2 pf = __half22float2(*reinterpret_cast<const __half2*>(&pu));
    return fmaf(cf.y, pf.y, fmaf(cf.x, pf.x, acc));
#endif
}

// ---------- 8-wave block sum (phase init only) ----------
__device__ __forceinline__ float block_reduce_sum(float v, float* red) {
    #pragma unroll
    for (int off = 32; off > 0; off >>= 1) v += __shfl_down(v, off, 64);
    const int wid = threadIdx.x >> 6, lane = threadIdx.x & 63;
    __syncthreads();
    if (lane == 0) red[wid] = v;
    __syncthreads();
    float s = 0.f;
    #pragma unroll
    for (int i = 0; i < 8; ++i) s += red[i];
    return s;
}

// ---------- fp32 matvec (refinement residual), proven ----------
__device__ __forceinline__ float matvec_assemble(float4 acc, float4* part, float4* w4_s) {
    const int tid = threadIdx.x;
    __syncthreads();
    part[tid] = acc;
    __syncthreads();
    if (tid < 128) {
        const float4 a0 = part[tid], a1 = part[tid + 128];
        const float4 a2 = part[tid + 256], a3 = part[tid + 384];
        float4 s4;
        s4.x = (a0.x + a1.x) + (a2.x + a3.x);
        s4.y = (a0.y + a1.y) + (a2.y + a3.y);
        s4.z = (a0.z + a1.z) + (a2.z + a3.z);
        s4.w = (a0.w + a1.w) + (a2.w + a3.w);
        w4_s[tid] = s4;
    }
    __syncthreads();
    return reinterpret_cast<const float*>(w4_s)[tid];
}

__device__ __forceinline__ float matvec32(const float4* __restrict__ Cq, const float* p_s,
                                          float4* part, float4* w4_s) {
    const int tid = threadIdx.x;
    const int g = tid >> 7, jq = tid & 127;
    float4 acc = make_float4(0.f, 0.f, 0.f, 0.f);
    int idx = g * 128 + jq;
    #pragma unroll 8
    for (int k = g; k < DIM; k += 4) {
        const float4 cv = Cq[idx];
        const float  pk = p_s[k];
        acc.x = fmaf(pk, cv.x, acc.x);
        acc.y = fmaf(pk, cv.y, acc.y);
        acc.z = fmaf(pk, cv.z, acc.z);
        acc.w = fmaf(pk, cv.w, acc.w);
        idx += 512;
    }
    return matvec_assemble(acc, part, w4_s);
}

// ---------- CG phase: fdot2 matvec, fp16 p, 3 barriers/iter ----------
// Merged 3-dot reduction; rsn = ||r - a w||^2 expanded analytically (exact
// algebra, robust to fp16-p). Depth-2 register prefetch of next-iter stream C
// (16 VGPR live across reduction — r8's spill was depth 6 / 48 VGPR).
__device__ float cg_phase(float bj, float a2, float s2,
                          const uint4* __restrict__ Cg, const uint4* C_lds,
                          unsigned short* p_h, float4* part, float* red,
                          int maxit, float tolf)
{
    const int tid = threadIdx.x;
    const int g   = tid >> 7;
    const int jq  = tid & 127;
    const uint2* p_h64 = (const uint2*)p_h;
    const float* partf = (const float*)part;

    float xj = 0.f, rj = bj, pj = bj;
    __syncthreads();                   // entry fence: prior readers of p_h/part done
    p_h[tid] = __half_as_ushort(__float2half(pj));

    // prologue prefetch: next matvec's first 2 stream steps (C only, no p dep)
    const int m0 = S2 + g, m1 = S2 + g + 4;
    uint4 pf0a = Cg[(2 * m0)     * 128 + jq];
    uint4 pf0b = Cg[(2 * m0 + 1) * 128 + jq];
    uint4 pf1a = Cg[(2 * m1)     * 128 + jq];
    uint4 pf1b = Cg[(2 * m1 + 1) * 128 + jq];

    float rs = block_reduce_sum(rj * rj, red);    // internal barriers publish p_h
    if (!(rs > 0.f)) return xj;                   // uniform
    const float tol = tolf * rs;

    for (int it = 0; it < maxit; ++it) {
        float4 acc = make_float4(0.f, 0.f, 0.f, 0.f);
        {   // prefetched steps first (registers already resident)
            const uint2 pu0 = p_h64[m0];
            acc.x = dot2acc(pf0b.x, pu0.y, dot2acc(pf0a.x, pu0.x, acc.x));
            acc.y = dot2acc(pf0b.y, pu0.y, dot2acc(pf0a.y, pu0.x, acc.y));
            acc.z = dot2acc(pf0b.z, pu0.y, dot2acc(pf0a.z, pu0.x, acc.z));
            acc.w = dot2acc(pf0b.w, pu0.y, dot2acc(pf0a.w, pu0.x, acc.w));
            const uint2 pu1 = p_h64[m1];
            acc.x = dot2acc(pf1b.x, pu1.y, dot2acc(pf1a.x, pu1.x, acc.x));
            acc.y = dot2acc(pf1b.y, pu1.y, dot2acc(pf1a.y, pu1.x, acc.y));
            acc.z = dot2acc(pf1b.z, pu1.y, dot2acc(pf1a.z, pu1.x, acc.z));
            acc.w = dot2acc(pf1b.w, pu1.y, dot2acc(pf1a.w, pu1.x, acc.w));
        }
        #pragma unroll
        for (int m = S2 + g + 8; m < MM; m += 4) {   // 21 fresh stream steps
            const uint4 cv0 = Cg[(2 * m)     * 128 + jq];
            const uint4 cv1 = Cg[(2 * m + 1) * 128 + jq];
            const uint2 pu  = p_h64[m];
            acc.x = dot2acc(cv1.x, pu.y, dot2acc(cv0.x, pu.x, acc.x));
            acc.y = dot2acc(cv1.y, pu.y, dot2acc(cv0.y, pu.x, acc.y));
            acc.z = dot2acc(cv1.z, pu.y, dot2acc(cv0.z, pu.x, acc.z));
            acc.w = dot2acc(cv1.w, pu.y, dot2acc(cv0.w, pu.x, acc.w));
        }
        #pragma unroll
        for (int m = g; m < S2; m += 4) {            // 9 slab steps from LDS
            const uint4 cv0 = C_lds[(2 * m)     * 128 + jq];
            const uint4 cv1 = C_lds[(2 * m + 1) * 128 + jq];
            const uint2 pu  = p_h64[m];
            acc.x = dot2acc(cv1.x, pu.y, dot2acc(cv0.x, pu.x, acc.x));
            acc.y = dot2acc(cv1.y, pu.y, dot2acc(cv0.y, pu.x, acc.y));
            acc.z = dot2acc(cv1.z, pu.y, dot2acc(cv0.z, pu.x, acc.z));
            acc.w = dot2acc(cv1.w, pu.y, dot2acc(cv0.w, pu.x, acc.w));
        }
        part[tid] = acc;

        // refill prefetch for NEXT iteration — issued before barrier A so the
        // vmcnt drain moves these bytes into the reduction window.
        pf0a = Cg[(2 * m0)     * 128 + jq];
        pf0b = Cg[(2 * m0 + 1) * 128 + jq];
        pf1a = Cg[(2 * m1)     * 128 + jq];
        pf1b = Cg[(2 * m1 + 1) * 128 + jq];

        __syncthreads();                                   // A: part published

        // self-assembly: w[tid] = sum over 4 groups (2-way bank alias = free)
        const float cw = partf[tid] + partf[512 + tid]
                       + partf[1024 + tid] + partf[1536 + tid];
        const float wj = fmaf(a2, cw, s2 * pj);

        // merged 3-dot partials
        float pwp = pj * wj, rwp = rj * wj, wwp = wj * wj;
        #pragma unroll
        for (int off = 32; off > 0; off >>= 1) {
            pwp += __shfl_down(pwp, off, 64);
            rwp += __shfl_down(rwp, off, 64);
            wwp += __shfl_down(wwp, off, 64);
        }
        if ((tid & 63) == 0) {
            const int w4 = (tid >> 6) * 4;
            red[w4] = pwp; red[w4 + 1] = rwp; red[w4 + 2] = wwp;
        }
        __syncthreads();                                   // B: partials published
        float pw = 0.f, rw = 0.f, ww = 0.f;
        #pragma unroll
        for (int w = 0; w < 8; ++w) {                      // uniform broadcast reads
            pw += red[w * 4]; rw += red[w * 4 + 1]; ww += red[w * 4 + 2];
        }
        pw = fmaxf(pw, 1e-30f);
        const float alpha = rs / pw;
        xj = fmaf( alpha, pj, xj);
        rj = fmaf(-alpha, wj, rj);
        // rsn = ||r_old - alpha w||^2 = rs - 2 a rw + a^2 ww  (exact expansion)
        const float rsn = fmaf(alpha * alpha, ww, fmaf(-2.0f * alpha, rw, rs));
        if (!(rsn > tol)) break;                           // uniform; NaN/neg safe
        const float beta = rsn / rs;
        rs = rsn;
        pj = fmaf(beta, pj, rj);
        p_h[tid] = __half_as_ushort(__float2half(pj));
        __syncthreads();                                   // D: p published
    }
    return xj;
}

// ---------- main solver: one block per item ----------
__global__ __launch_bounds__(NTHR, 1)
void vps_solve_kernel(const float* __restrict__ t_arr,
                      const float* __restrict__ x_arr,
                      const float* __restrict__ mean0,
                      const float* __restrict__ cov0,
                      const uint4* __restrict__ Cp,
                      float* __restrict__ out)
{
    __shared__ uint4  C_lds[SLABKK * 128];                 // 144 KB slab
    __shared__ float4 part[NTHR];                          // 8 KB
    __shared__ float4 p4_s[DIM / 4];                       // 2 KB (refinement p)
    __shared__ float4 w4_s[DIM / 4];                       // 2 KB (refinement w)
    __shared__ __align__(8) unsigned short p_h[DIM];       // 1 KB
    __shared__ float  red[32];
    float* p_s = (float*)p4_s;

    const int b   = blockIdx.x;
    const int tid = threadIdx.x;

    const float t  = t_arr[b];
    const float ib = 0.1f * t + 9.95f * t * t;
    const float a  = expf(-0.5f * ib);
    const float a2 = a * a;
    const float s2 = fmaxf(1.0f - a2, 1e-12f);

    const float rhs = x_arr[b * DIM + tid] - a * mean0[tid];

    // load slab once (coalesced uint4; 18 per thread)
    for (int i = tid; i < SLABKK * 128; i += NTHR) C_lds[i] = Cp[i];
    // cg_phase's entry barriers make the slab visible before the first matvec.

    // Phase 1: CG on fp16 pair-packed matrix (rel-r ~4.5e-2)
    const float x1 = cg_phase(rhs, a2, s2, Cp, C_lds, p_h, part, red, 20, 2e-3f);

    // Exact fp32 residual
    __syncthreads();
    p_s[tid] = x1;
    __syncthreads();
    const float cw  = matvec32(reinterpret_cast<const float4*>(cov0), p_s, part, w4_s);
    const float rtj = rhs - (a2 * cw + s2 * x1);

    // Phase 2: correction solve (absorbs fp16 matrix + fp16-p perturbation)
    const float z = cg_phase(rtj, a2, s2, Cp, C_lds, p_h, part, red, 18, 7e-3f);

    out[b * DIM + tid] = -(x1 + z);
}

// ---------- pack cov0 -> pair-interleaved fp16 (proven) ----------
__global__ void conv_pack_kernel(const float* __restrict__ C, unsigned int* __restrict__ out) {
    const int id = blockIdx.x * 256 + threadIdx.x;   // 131072 total
    const int kk = id >> 9;
    const int j  = id & 511;
    const __half2 h = __floats2half2_rn(C[(2 * kk) * DIM + j], C[(2 * kk + 1) * DIM + j]);
    out[id] = *reinterpret_cast<const unsigned int*>(&h);
}

// ================= fallback path (ws too small): proven fp32 CG =================
__global__ __launch_bounds__(NTHR, 1)
void vps_cg_kernel(const float* __restrict__ t_arr, const float* __restrict__ x_arr,
                   const float* __restrict__ mean0, const float* __restrict__ cov0,
                   float* __restrict__ out)
{
    const int b = blockIdx.x, tid = threadIdx.x;
    __shared__ float4 part[NTHR];
    __shared__ float4 p4_s[DIM / 4];
    __shared__ float4 w4_s[DIM / 4];
    __shared__ float  red[16];
    float* p_s = (float*)p4_s;
    const float t  = t_arr[b];
    const float ib = 0.1f * t + 9.95f * t * t;
    const float a  = expf(-0.5f * ib);
    const float a2 = a * a;
    const float s2 = fmaxf(1.0f - a2, 1e-12f);
    const float rhs = x_arr[b * DIM + tid] - a * mean0[tid];
    float xj = 0.f, rj = rhs, pj = rhs;
    p_s[tid] = pj;
    float rs = block_reduce_sum(rj * rj, red);
    const float tol = rs * 1e-12f;
    for (int it = 0; it < 72; ++it) {
        const float cw = matvec32(reinterpret_cast<const float4*>(cov0), p_s, part, w4_s);
        const float wj = a2 * cw + s2 * pj;
        const float pw = block_reduce_sum(pj * wj, red);
        const float alpha = rs / fmaxf(pw, 1e-37f);
        xj = fmaf(alpha, pj, xj);
        rj = fmaf(-alpha, wj, rj);
        const float rsn = block_reduce_sum(rj * rj, red);
        if (rsn < tol) break;
        const float beta = rsn / fmaxf(rs, 1e-37f);
        pj = fmaf(beta, pj, rj);
        rs = rsn;
        p_s[tid] = pj;
        __syncthreads();
    }
    out[b * DIM + tid] = -xj;
}

extern "C" void kernel_launch(void* const* d_in, const int* in_sizes, int n_in,
                              void* d_out, int out_size, void* d_ws, size_t ws_size,
                              hipStream_t stream) {
    const float* t_arr = (const float*)d_in[0];
    const float* x_arr = (const float*)d_in[1];
    const float* m0    = (const float*)d_in[2];
    const float* c0    = (const float*)d_in[3];
    float* out = (float*)d_out;
    const int B = in_sizes[0];   // 128
    const size_t need = (size_t)NKK * DIM * 4;   // 512 KB packed fp16
    if (ws_size >= need) {
        hipLaunchKernelGGL(conv_pack_kernel, dim3(NKK * DIM / 256), dim3(256), 0, stream,
                           c0, (unsigned int*)d_ws);
        hipLaunchKernelGGL(vps_solve_kernel, dim3(B), dim3(NTHR), 0, stream,
                           t_arr, x_arr, m0, c0, (const uint4*)d_ws, out);
    } else {
        hipLaunchKernelGGL(vps_cg_kernel, dim3(B), dim3(NTHR), 0, stream,
                           t_arr, x_arr, m0, c0, out);
    }
}

// Round 12
// 109.921 us; speedup vs baseline: 3.5650x; 1.1136x over previous
//
#include <hip/hip_runtime.h>
#include <hip/hip_fp16.h>
#include <math.h>

#define DIM    512
#define NTHR   512
#define NKK    256          // pair-rows (2 matrix rows per pair)
#define SLABKK 72           // pair-rows in LDS (72 * 2KB = 144 KB); % 8 == 0
#define MM     (DIM / 4)    // 128 pair-pair steps
#define S2     (SLABKK / 2) // 36: first streamed pair-pair step

typedef _Float16 h2_t __attribute__((ext_vector_type(2)));

#if defined(__has_builtin)
#  if __has_builtin(__builtin_amdgcn_fdot2)
#    define HAVE_FDOT2 1
#  endif
#endif
#ifndef HAVE_FDOT2
#  define HAVE_FDOT2 0
#endif

// acc += C_pair . p_pair (2 MACs, fp32 accumulate) — proven numerics
__device__ __forceinline__ float dot2acc(unsigned int cu, unsigned int pu, float acc) {
#if HAVE_FDOT2
    return __builtin_amdgcn_fdot2(__builtin_bit_cast(h2_t, cu),
                                  __builtin_bit_cast(h2_t, pu), acc, false);
#else
    const float2 cf = __half22float2(*reinterpret_cast<const __half2*>(&cu));
    const float2 pf = __half22float2(*reinterpret_cast<const __half2*>(&pu));
    return fmaf(cf.y, pf.y, fmaf(cf.x, pf.x, acc));
#endif
}

// fused: acc += dot2(cv0, pu.x) + dot2(cv1, pu.y) over a uint4 pair
#define ACC_STEP(acc, cv0, cv1, pu)                                   \
    do {                                                              \
        (acc).x = dot2acc((cv1).x, (pu).y, dot2acc((cv0).x, (pu).x, (acc).x)); \
        (acc).y = dot2acc((cv1).y, (pu).y, dot2acc((cv0).y, (pu).x, (acc).y)); \
        (acc).z = dot2acc((cv1).z, (pu).y, dot2acc((cv0).z, (pu).x, (acc).z)); \
        (acc).w = dot2acc((cv1).w, (pu).y, dot2acc((cv0).w, (pu).x, (acc).w)); \
    } while (0)

// ---------- 8-wave block sum (phase init only) ----------
__device__ __forceinline__ float block_reduce_sum(float v, float* red) {
    #pragma unroll
    for (int off = 32; off > 0; off >>= 1) v += __shfl_down(v, off, 64);
    const int wid = threadIdx.x >> 6, lane = threadIdx.x & 63;
    __syncthreads();
    if (lane == 0) red[wid] = v;
    __syncthreads();
    float s = 0.f;
    #pragma unroll
    for (int i = 0; i < 8; ++i) s += red[i];
    return s;
}

// ---------- fp32 matvec (refinement residual), proven ----------
__device__ __forceinline__ float matvec_assemble(float4 acc, float4* part, float4* w4_s) {
    const int tid = threadIdx.x;
    __syncthreads();
    part[tid] = acc;
    __syncthreads();
    if (tid < 128) {
        const float4 a0 = part[tid], a1 = part[tid + 128];
        const float4 a2 = part[tid + 256], a3 = part[tid + 384];
        float4 s4;
        s4.x = (a0.x + a1.x) + (a2.x + a3.x);
        s4.y = (a0.y + a1.y) + (a2.y + a3.y);
        s4.z = (a0.z + a1.z) + (a2.z + a3.z);
        s4.w = (a0.w + a1.w) + (a2.w + a3.w);
        w4_s[tid] = s4;
    }
    __syncthreads();
    return reinterpret_cast<const float*>(w4_s)[tid];
}

__device__ __forceinline__ float matvec32(const float4* __restrict__ Cq, const float* p_s,
                                          float4* part, float4* w4_s) {
    const int tid = threadIdx.x;
    const int g = tid >> 7, jq = tid & 127;
    float4 acc = make_float4(0.f, 0.f, 0.f, 0.f);
    int idx = g * 128 + jq;
    #pragma unroll 8
    for (int k = g; k < DIM; k += 4) {
        const float4 cv = Cq[idx];
        const float  pk = p_s[k];
        acc.x = fmaf(pk, cv.x, acc.x);
        acc.y = fmaf(pk, cv.y, acc.y);
        acc.z = fmaf(pk, cv.z, acc.z);
        acc.w = fmaf(pk, cv.w, acc.w);
        idx += 512;
    }
    return matvec_assemble(acc, part, w4_s);
}

// ---------- CG phase: fdot2 matvec, fp16 p, 3 barriers/iter ----------
// Merged 3-dot reduction; rsn = ||r - a w||^2 expanded analytically (exact
// algebra, robust to fp16-p). Depth-4 register prefetch of next-iter stream C
// (8 named uint4 = 32 VGPR live across barrier; r8's spill was 48).
__device__ float cg_phase(float bj, float a2, float s2,
                          const uint4* __restrict__ Cg, const uint4* C_lds,
                          unsigned short* p_h, float4* part, float* red,
                          int maxit, float tolf)
{
    const int tid = threadIdx.x;
    const int g   = tid >> 7;
    const int jq  = tid & 127;
    const uint2* p_h64 = (const uint2*)p_h;
    const float* partf = (const float*)part;

    float xj = 0.f, rj = bj, pj = bj;
    __syncthreads();                   // entry fence: prior readers of p_h/part done
    p_h[tid] = __half_as_ushort(__float2half(pj));

    // prologue prefetch: next matvec's first 4 stream steps (C only, no p dep)
    const int m0 = S2 + g, m1 = m0 + 4, m2 = m0 + 8, m3 = m0 + 12;
    uint4 pf0a = Cg[(2 * m0)     * 128 + jq];
    uint4 pf0b = Cg[(2 * m0 + 1) * 128 + jq];
    uint4 pf1a = Cg[(2 * m1)     * 128 + jq];
    uint4 pf1b = Cg[(2 * m1 + 1) * 128 + jq];
    uint4 pf2a = Cg[(2 * m2)     * 128 + jq];
    uint4 pf2b = Cg[(2 * m2 + 1) * 128 + jq];
    uint4 pf3a = Cg[(2 * m3)     * 128 + jq];
    uint4 pf3b = Cg[(2 * m3 + 1) * 128 + jq];

    float rs = block_reduce_sum(rj * rj, red);    // internal barriers publish p_h
    if (!(rs > 0.f)) return xj;                   // uniform
    const float tol = tolf * rs;

    for (int it = 0; it < maxit; ++it) {
        float4 acc = make_float4(0.f, 0.f, 0.f, 0.f);
        {   // prefetched steps first (registers already resident)
            const uint2 pu0 = p_h64[m0]; ACC_STEP(acc, pf0a, pf0b, pu0);
            const uint2 pu1 = p_h64[m1]; ACC_STEP(acc, pf1a, pf1b, pu1);
            const uint2 pu2 = p_h64[m2]; ACC_STEP(acc, pf2a, pf2b, pu2);
            const uint2 pu3 = p_h64[m3]; ACC_STEP(acc, pf3a, pf3b, pu3);
        }
        #pragma unroll
        for (int m = S2 + g + 16; m < MM; m += 4) {  // 19 fresh stream steps
            const uint4 cv0 = Cg[(2 * m)     * 128 + jq];
            const uint4 cv1 = Cg[(2 * m + 1) * 128 + jq];
            const uint2 pu  = p_h64[m];
            ACC_STEP(acc, cv0, cv1, pu);
        }
        #pragma unroll
        for (int m = g; m < S2; m += 4) {            // 9 slab steps from LDS
            const uint4 cv0 = C_lds[(2 * m)     * 128 + jq];
            const uint4 cv1 = C_lds[(2 * m + 1) * 128 + jq];
            const uint2 pu  = p_h64[m];
            ACC_STEP(acc, cv0, cv1, pu);
        }
        part[tid] = acc;

        // refill prefetch for NEXT iteration — issued before barrier A so the
        // vmcnt drain moves these bytes into the reduction window.
        pf0a = Cg[(2 * m0)     * 128 + jq];
        pf0b = Cg[(2 * m0 + 1) * 128 + jq];
        pf1a = Cg[(2 * m1)     * 128 + jq];
        pf1b = Cg[(2 * m1 + 1) * 128 + jq];
        pf2a = Cg[(2 * m2)     * 128 + jq];
        pf2b = Cg[(2 * m2 + 1) * 128 + jq];
        pf3a = Cg[(2 * m3)     * 128 + jq];
        pf3b = Cg[(2 * m3 + 1) * 128 + jq];

        __syncthreads();                                   // A: part published

        // self-assembly: w[tid] = sum over 4 groups (2-way bank alias = free)
        const float cw = partf[tid] + partf[512 + tid]
                       + partf[1024 + tid] + partf[1536 + tid];
        const float wj = fmaf(a2, cw, s2 * pj);

        // merged 3-dot partials
        float pwp = pj * wj, rwp = rj * wj, wwp = wj * wj;
        #pragma unroll
        for (int off = 32; off > 0; off >>= 1) {
            pwp += __shfl_down(pwp, off, 64);
            rwp += __shfl_down(rwp, off, 64);
            wwp += __shfl_down(wwp, off, 64);
        }
        if ((tid & 63) == 0) {
            const int w4 = (tid >> 6) * 4;
            red[w4] = pwp; red[w4 + 1] = rwp; red[w4 + 2] = wwp;
        }
        __syncthreads();                                   // B: partials published
        float pw = 0.f, rw = 0.f, ww = 0.f;
        #pragma unroll
        for (int w = 0; w < 8; ++w) {                      // uniform broadcast reads
            pw += red[w * 4]; rw += red[w * 4 + 1]; ww += red[w * 4 + 2];
        }
        pw = fmaxf(pw, 1e-30f);
        const float alpha = rs / pw;
        xj = fmaf( alpha, pj, xj);
        rj = fmaf(-alpha, wj, rj);
        // rsn = ||r_old - alpha w||^2 = rs - 2 a rw + a^2 ww  (exact expansion)
        const float rsn = fmaf(alpha * alpha, ww, fmaf(-2.0f * alpha, rw, rs));
        if (!(rsn > tol)) break;                           // uniform; NaN/neg safe
        const float beta = rsn / rs;
        rs = rsn;
        pj = fmaf(beta, pj, rj);
        p_h[tid] = __half_as_ushort(__float2half(pj));
        __syncthreads();                                   // D: p published
    }
    return xj;
}

// ---------- main solver: one block per item ----------
__global__ __launch_bounds__(NTHR, 1)
void vps_solve_kernel(const float* __restrict__ t_arr,
                      const float* __restrict__ x_arr,
                      const float* __restrict__ mean0,
                      const float* __restrict__ cov0,
                      const uint4* __restrict__ Cp,
                      float* __restrict__ out)
{
    __shared__ uint4  C_lds[SLABKK * 128];                 // 144 KB slab
    __shared__ float4 part[NTHR];                          // 8 KB
    __shared__ float4 p4_s[DIM / 4];                       // 2 KB (refinement p)
    __shared__ float4 w4_s[DIM / 4];                       // 2 KB (refinement w)
    __shared__ __align__(8) unsigned short p_h[DIM];       // 1 KB
    __shared__ float  red[32];
    float* p_s = (float*)p4_s;

    const int b   = blockIdx.x;
    const int tid = threadIdx.x;

    const float t  = t_arr[b];
    const float ib = 0.1f * t + 9.95f * t * t;
    const float a  = expf(-0.5f * ib);
    const float a2 = a * a;
    const float s2 = fmaxf(1.0f - a2, 1e-12f);

    const float rhs = x_arr[b * DIM + tid] - a * mean0[tid];

    // load slab once (coalesced uint4; 18 per thread)
    for (int i = tid; i < SLABKK * 128; i += NTHR) C_lds[i] = Cp[i];
    // cg_phase's entry barriers make the slab visible before the first matvec.

    // Phase 1: CG on fp16 pair-packed matrix (rel-r ~6.3e-2)
    const float x1 = cg_phase(rhs, a2, s2, Cp, C_lds, p_h, part, red, 20, 4e-3f);

    // Exact fp32 residual
    __syncthreads();
    p_s[tid] = x1;
    __syncthreads();
    const float cw  = matvec32(reinterpret_cast<const float4*>(cov0), p_s, part, w4_s);
    const float rtj = rhs - (a2 * cw + s2 * x1);

    // Phase 2: correction solve (absorbs fp16 matrix + fp16-p perturbation)
    const float z = cg_phase(rtj, a2, s2, Cp, C_lds, p_h, part, red, 18, 1.2e-2f);

    out[b * DIM + tid] = -(x1 + z);
}

// ---------- pack cov0 -> pair-interleaved fp16 (proven) ----------
__global__ void conv_pack_kernel(const float* __restrict__ C, unsigned int* __restrict__ out) {
    const int id = blockIdx.x * 256 + threadIdx.x;   // 131072 total
    const int kk = id >> 9;
    const int j  = id & 511;
    const __half2 h = __floats2half2_rn(C[(2 * kk) * DIM + j], C[(2 * kk + 1) * DIM + j]);
    out[id] = *reinterpret_cast<const unsigned int*>(&h);
}

// ================= fallback path (ws too small): proven fp32 CG =================
__global__ __launch_bounds__(NTHR, 1)
void vps_cg_kernel(const float* __restrict__ t_arr, const float* __restrict__ x_arr,
                   const float* __restrict__ mean0, const float* __restrict__ cov0,
                   float* __restrict__ out)
{
    const int b = blockIdx.x, tid = threadIdx.x;
    __shared__ float4 part[NTHR];
    __shared__ float4 p4_s[DIM / 4];
    __shared__ float4 w4_s[DIM / 4];
    __shared__ float  red[16];
    float* p_s = (float*)p4_s;
    const float t  = t_arr[b];
    const float ib = 0.1f * t + 9.95f * t * t;
    const float a  = expf(-0.5f * ib);
    const float a2 = a * a;
    const float s2 = fmaxf(1.0f - a2, 1e-12f);
    const float rhs = x_arr[b * DIM + tid] - a * mean0[tid];
    float xj = 0.f, rj = rhs, pj = rhs;
    p_s[tid] = pj;
    float rs = block_reduce_sum(rj * rj, red);
    const float tol = rs * 1e-12f;
    for (int it = 0; it < 72; ++it) {
        const float cw = matvec32(reinterpret_cast<const float4*>(cov0), p_s, part, w4_s);
        const float wj = a2 * cw + s2 * pj;
        const float pw = block_reduce_sum(pj * wj, red);
        const float alpha = rs / fmaxf(pw, 1e-37f);
        xj = fmaf(alpha, pj, xj);
        rj = fmaf(-alpha, wj, rj);
        const float rsn = block_reduce_sum(rj * rj, red);
        if (rsn < tol) break;
        const float beta = rsn / fmaxf(rs, 1e-37f);
        pj = fmaf(beta, pj, rj);
        rs = rsn;
        p_s[tid] = pj;
        __syncthreads();
    }
    out[b * DIM + tid] = -xj;
}

extern "C" void kernel_launch(void* const* d_in, const int* in_sizes, int n_in,
                              void* d_out, int out_size, void* d_ws, size_t ws_size,
                              hipStream_t stream) {
    const float* t_arr = (const float*)d_in[0];
    const float* x_arr = (const float*)d_in[1];
    const float* m0    = (const float*)d_in[2];
    const float* c0    = (const float*)d_in[3];
    float* out = (float*)d_out;
    const int B = in_sizes[0];   // 128
    const size_t need = (size_t)NKK * DIM * 4;   // 512 KB packed fp16
    if (ws_size >= need) {
        hipLaunchKernelGGL(conv_pack_kernel, dim3(NKK * DIM / 256), dim3(256), 0, stream,
                           c0, (unsigned int*)d_ws);
        hipLaunchKernelGGL(vps_solve_kernel, dim3(B), dim3(NTHR), 0, stream,
                           t_arr, x_arr, m0, c0, (const uint4*)d_ws, out);
    } else {
        hipLaunchKernelGGL(vps_cg_kernel, dim3(B), dim3(NTHR), 0, stream,
                           t_arr, x_arr, m0, c0, out);
    }
}

// Round 13
// 100.298 us; speedup vs baseline: 3.9071x; 1.0959x over previous
//
#include <hip/hip_runtime.h>
#include <hip/hip_fp16.h>
#include <math.h>

#define DIM    512
#define NTHR   512
#define NKK    256          // pair-rows (2 matrix rows per pair)
#define SLABKK 72           // pair-rows in LDS (72 * 2KB = 144 KB); % 8 == 0
#define MM     (DIM / 4)    // 128 pair-pair steps
#define S2     (SLABKK / 2) // 36: first streamed pair-pair step

typedef _Float16 h2_t __attribute__((ext_vector_type(2)));

#if defined(__has_builtin)
#  if __has_builtin(__builtin_amdgcn_fdot2)
#    define HAVE_FDOT2 1
#  endif
#endif
#ifndef HAVE_FDOT2
#  define HAVE_FDOT2 0
#endif

// acc += C_pair . p_pair (2 MACs, fp32 accumulate) — proven numerics
__device__ __forceinline__ float dot2acc(unsigned int cu, unsigned int pu, float acc) {
#if HAVE_FDOT2
    return __builtin_amdgcn_fdot2(__builtin_bit_cast(h2_t, cu),
                                  __builtin_bit_cast(h2_t, pu), acc, false);
#else
    const float2 cf = __half22float2(*reinterpret_cast<const __half2*>(&cu));
    const float2 pf = __half22float2(*reinterpret_cast<const __half2*>(&pu));
    return fmaf(cf.y, pf.y, fmaf(cf.x, pf.x, acc));
#endif
}

// fused: acc += dot2(cv0, pu.x) + dot2(cv1, pu.y) over a uint4 pair
#define ACC_STEP(acc, cv0, cv1, pu)                                   \
    do {                                                              \
        (acc).x = dot2acc((cv1).x, (pu).y, dot2acc((cv0).x, (pu).x, (acc).x)); \
        (acc).y = dot2acc((cv1).y, (pu).y, dot2acc((cv0).y, (pu).x, (acc).y)); \
        (acc).z = dot2acc((cv1).z, (pu).y, dot2acc((cv0).z, (pu).x, (acc).z)); \
        (acc).w = dot2acc((cv1).w, (pu).y, dot2acc((cv0).w, (pu).x, (acc).w)); \
    } while (0)

// ---------- 8-wave block sum (phase init only) ----------
__device__ __forceinline__ float block_reduce_sum(float v, float* red) {
    #pragma unroll
    for (int off = 32; off > 0; off >>= 1) v += __shfl_down(v, off, 64);
    const int wid = threadIdx.x >> 6, lane = threadIdx.x & 63;
    __syncthreads();
    if (lane == 0) red[wid] = v;
    __syncthreads();
    float s = 0.f;
    #pragma unroll
    for (int i = 0; i < 8; ++i) s += red[i];
    return s;
}

// ---------- fp32 matvec (refinement residual), proven ----------
__device__ __forceinline__ float matvec_assemble(float4 acc, float4* part, float4* w4_s) {
    const int tid = threadIdx.x;
    __syncthreads();
    part[tid] = acc;
    __syncthreads();
    if (tid < 128) {
        const float4 a0 = part[tid], a1 = part[tid + 128];
        const float4 a2 = part[tid + 256], a3 = part[tid + 384];
        float4 s4;
        s4.x = (a0.x + a1.x) + (a2.x + a3.x);
        s4.y = (a0.y + a1.y) + (a2.y + a3.y);
        s4.z = (a0.z + a1.z) + (a2.z + a3.z);
        s4.w = (a0.w + a1.w) + (a2.w + a3.w);
        w4_s[tid] = s4;
    }
    __syncthreads();
    return reinterpret_cast<const float*>(w4_s)[tid];
}

__device__ __forceinline__ float matvec32(const float4* __restrict__ Cq, const float* p_s,
                                          float4* part, float4* w4_s) {
    const int tid = threadIdx.x;
    const int g = tid >> 7, jq = tid & 127;
    float4 acc = make_float4(0.f, 0.f, 0.f, 0.f);
    int idx = g * 128 + jq;
    #pragma unroll 8
    for (int k = g; k < DIM; k += 4) {
        const float4 cv = Cq[idx];
        const float  pk = p_s[k];
        acc.x = fmaf(pk, cv.x, acc.x);
        acc.y = fmaf(pk, cv.y, acc.y);
        acc.z = fmaf(pk, cv.z, acc.z);
        acc.w = fmaf(pk, cv.w, acc.w);
        idx += 512;
    }
    return matvec_assemble(acc, part, w4_s);
}

// ---------- CG phase: fdot2 matvec, fp16 p, 3 barriers/iter ----------
// Merged 3-dot reduction; rsn = ||r - a w||^2 expanded analytically (exact
// algebra, robust to fp16-p). Depth-6 register prefetch of next-iter stream C
// (12 named uint4; fills the ~0.6 µs reduction window with 96 KB of stream).
__device__ float cg_phase(float bj, float a2, float s2,
                          const uint4* __restrict__ Cg, const uint4* C_lds,
                          unsigned short* p_h, float4* part, float* red,
                          int maxit, float tolf)
{
    const int tid = threadIdx.x;
    const int g   = tid >> 7;
    const int jq  = tid & 127;
    const uint2* p_h64 = (const uint2*)p_h;
    const float* partf = (const float*)part;

    float xj = 0.f, rj = bj, pj = bj;
    __syncthreads();                   // entry fence: prior readers of p_h/part done
    p_h[tid] = __half_as_ushort(__float2half(pj));

    // prologue prefetch: next matvec's first 6 stream steps (C only, no p dep)
    const int m0 = S2 + g, m1 = m0 + 4, m2 = m0 + 8,
              m3 = m0 + 12, m4 = m0 + 16, m5 = m0 + 20;
    uint4 pf0a = Cg[(2 * m0)     * 128 + jq];
    uint4 pf0b = Cg[(2 * m0 + 1) * 128 + jq];
    uint4 pf1a = Cg[(2 * m1)     * 128 + jq];
    uint4 pf1b = Cg[(2 * m1 + 1) * 128 + jq];
    uint4 pf2a = Cg[(2 * m2)     * 128 + jq];
    uint4 pf2b = Cg[(2 * m2 + 1) * 128 + jq];
    uint4 pf3a = Cg[(2 * m3)     * 128 + jq];
    uint4 pf3b = Cg[(2 * m3 + 1) * 128 + jq];
    uint4 pf4a = Cg[(2 * m4)     * 128 + jq];
    uint4 pf4b = Cg[(2 * m4 + 1) * 128 + jq];
    uint4 pf5a = Cg[(2 * m5)     * 128 + jq];
    uint4 pf5b = Cg[(2 * m5 + 1) * 128 + jq];

    float rs = block_reduce_sum(rj * rj, red);    // internal barriers publish p_h
    if (!(rs > 0.f)) return xj;                   // uniform
    const float tol = tolf * rs;

    for (int it = 0; it < maxit; ++it) {
        float4 acc = make_float4(0.f, 0.f, 0.f, 0.f);
        {   // prefetched steps first (registers already resident)
            const uint2 pu0 = p_h64[m0]; ACC_STEP(acc, pf0a, pf0b, pu0);
            const uint2 pu1 = p_h64[m1]; ACC_STEP(acc, pf1a, pf1b, pu1);
            const uint2 pu2 = p_h64[m2]; ACC_STEP(acc, pf2a, pf2b, pu2);
            const uint2 pu3 = p_h64[m3]; ACC_STEP(acc, pf3a, pf3b, pu3);
            const uint2 pu4 = p_h64[m4]; ACC_STEP(acc, pf4a, pf4b, pu4);
            const uint2 pu5 = p_h64[m5]; ACC_STEP(acc, pf5a, pf5b, pu5);
        }
        #pragma unroll
        for (int m = S2 + g + 24; m < MM; m += 4) {  // 17 fresh stream steps
            const uint4 cv0 = Cg[(2 * m)     * 128 + jq];
            const uint4 cv1 = Cg[(2 * m + 1) * 128 + jq];
            const uint2 pu  = p_h64[m];
            ACC_STEP(acc, cv0, cv1, pu);
        }
        #pragma unroll
        for (int m = g; m < S2; m += 4) {            // 9 slab steps from LDS
            const uint4 cv0 = C_lds[(2 * m)     * 128 + jq];
            const uint4 cv1 = C_lds[(2 * m + 1) * 128 + jq];
            const uint2 pu  = p_h64[m];
            ACC_STEP(acc, cv0, cv1, pu);
        }
        part[tid] = acc;

        // refill prefetch for NEXT iteration — issued before barrier A so the
        // vmcnt drain moves these 96 KB into the reduction window.
        pf0a = Cg[(2 * m0)     * 128 + jq];
        pf0b = Cg[(2 * m0 + 1) * 128 + jq];
        pf1a = Cg[(2 * m1)     * 128 + jq];
        pf1b = Cg[(2 * m1 + 1) * 128 + jq];
        pf2a = Cg[(2 * m2)     * 128 + jq];
        pf2b = Cg[(2 * m2 + 1) * 128 + jq];
        pf3a = Cg[(2 * m3)     * 128 + jq];
        pf3b = Cg[(2 * m3 + 1) * 128 + jq];
        pf4a = Cg[(2 * m4)     * 128 + jq];
        pf4b = Cg[(2 * m4 + 1) * 128 + jq];
        pf5a = Cg[(2 * m5)     * 128 + jq];
        pf5b = Cg[(2 * m5 + 1) * 128 + jq];

        __syncthreads();                                   // A: part published

        // self-assembly: w[tid] = sum over 4 groups (2-way bank alias = free)
        const float cw = partf[tid] + partf[512 + tid]
                       + partf[1024 + tid] + partf[1536 + tid];
        const float wj = fmaf(a2, cw, s2 * pj);

        // merged 3-dot partials
        float pwp = pj * wj, rwp = rj * wj, wwp = wj * wj;
        #pragma unroll
        for (int off = 32; off > 0; off >>= 1) {
            pwp += __shfl_down(pwp, off, 64);
            rwp += __shfl_down(rwp, off, 64);
            wwp += __shfl_down(wwp, off, 64);
        }
        if ((tid & 63) == 0) {
            const int w4 = (tid >> 6) * 4;
            red[w4] = pwp; red[w4 + 1] = rwp; red[w4 + 2] = wwp;
        }
        __syncthreads();                                   // B: partials published
        float pw = 0.f, rw = 0.f, ww = 0.f;
        #pragma unroll
        for (int w = 0; w < 8; ++w) {                      // uniform broadcast reads
            pw += red[w * 4]; rw += red[w * 4 + 1]; ww += red[w * 4 + 2];
        }
        pw = fmaxf(pw, 1e-30f);
        const float alpha = rs / pw;
        xj = fmaf( alpha, pj, xj);
        rj = fmaf(-alpha, wj, rj);
        // rsn = ||r_old - alpha w||^2 = rs - 2 a rw + a^2 ww  (exact expansion)
        const float rsn = fmaf(alpha * alpha, ww, fmaf(-2.0f * alpha, rw, rs));
        if (!(rsn > tol)) break;                           // uniform; NaN/neg safe
        const float beta = rsn / rs;
        rs = rsn;
        pj = fmaf(beta, pj, rj);
        p_h[tid] = __half_as_ushort(__float2half(pj));
        __syncthreads();                                   // D: p published
    }
    return xj;
}

// ---------- main solver: one block per item ----------
__global__ __launch_bounds__(NTHR, 1)
void vps_solve_kernel(const float* __restrict__ t_arr,
                      const float* __restrict__ x_arr,
                      const float* __restrict__ mean0,
                      const float* __restrict__ cov0,
                      const uint4* __restrict__ Cp,
                      float* __restrict__ out)
{
    __shared__ uint4  C_lds[SLABKK * 128];                 // 144 KB slab
    __shared__ float4 part[NTHR];                          // 8 KB
    __shared__ float4 p4_s[DIM / 4];                       // 2 KB (refinement p)
    __shared__ float4 w4_s[DIM / 4];                       // 2 KB (refinement w)
    __shared__ __align__(8) unsigned short p_h[DIM];       // 1 KB
    __shared__ float  red[32];
    float* p_s = (float*)p4_s;

    const int b   = blockIdx.x;
    const int tid = threadIdx.x;

    const float t  = t_arr[b];
    const float ib = 0.1f * t + 9.95f * t * t;
    const float a  = expf(-0.5f * ib);
    const float a2 = a * a;
    const float s2 = fmaxf(1.0f - a2, 1e-12f);

    const float rhs = x_arr[b * DIM + tid] - a * mean0[tid];

    // load slab once (coalesced uint4; 18 per thread)
    for (int i = tid; i < SLABKK * 128; i += NTHR) C_lds[i] = Cp[i];
    // cg_phase's entry barriers make the slab visible before the first matvec.

    // Phase 1: CG on fp16 pair-packed matrix (rel-r ~7.7e-2)
    const float x1 = cg_phase(rhs, a2, s2, Cp, C_lds, p_h, part, red, 20, 6e-3f);

    // Exact fp32 residual
    __syncthreads();
    p_s[tid] = x1;
    __syncthreads();
    const float cw  = matvec32(reinterpret_cast<const float4*>(cov0), p_s, part, w4_s);
    const float rtj = rhs - (a2 * cw + s2 * x1);

    // Phase 2: correction solve (absorbs fp16 matrix + fp16-p perturbation)
    const float z = cg_phase(rtj, a2, s2, Cp, C_lds, p_h, part, red, 18, 2e-2f);

    out[b * DIM + tid] = -(x1 + z);
}

// ---------- pack cov0 -> pair-interleaved fp16 (proven) ----------
__global__ void conv_pack_kernel(const float* __restrict__ C, unsigned int* __restrict__ out) {
    const int id = blockIdx.x * 256 + threadIdx.x;   // 131072 total
    const int kk = id >> 9;
    const int j  = id & 511;
    const __half2 h = __floats2half2_rn(C[(2 * kk) * DIM + j], C[(2 * kk + 1) * DIM + j]);
    out[id] = *reinterpret_cast<const unsigned int*>(&h);
}

// ================= fallback path (ws too small): proven fp32 CG =================
__global__ __launch_bounds__(NTHR, 1)
void vps_cg_kernel(const float* __restrict__ t_arr, const float* __restrict__ x_arr,
                   const float* __restrict__ mean0, const float* __restrict__ cov0,
                   float* __restrict__ out)
{
    const int b = blockIdx.x, tid = threadIdx.x;
    __shared__ float4 part[NTHR];
    __shared__ float4 p4_s[DIM / 4];
    __shared__ float4 w4_s[DIM / 4];
    __shared__ float  red[16];
    float* p_s = (float*)p4_s;
    const float t  = t_arr[b];
    const float ib = 0.1f * t + 9.95f * t * t;
    const float a  = expf(-0.5f * ib);
    const float a2 = a * a;
    const float s2 = fmaxf(1.0f - a2, 1e-12f);
    const float rhs = x_arr[b * DIM + tid] - a * mean0[tid];
    float xj = 0.f, rj = rhs, pj = rhs;
    p_s[tid] = pj;
    float rs = block_reduce_sum(rj * rj, red);
    const float tol = rs * 1e-12f;
    for (int it = 0; it < 72; ++it) {
        const float cw = matvec32(reinterpret_cast<const float4*>(cov0), p_s, part, w4_s);
        const float wj = a2 * cw + s2 * pj;
        const float pw = block_reduce_sum(pj * wj, red);
        const float alpha = rs / fmaxf(pw, 1e-37f);
        xj = fmaf(alpha, pj, xj);
        rj = fmaf(-alpha, wj, rj);
        const float rsn = block_reduce_sum(rj * rj, red);
        if (rsn < tol) break;
        const float beta = rsn / fmaxf(rs, 1e-37f);
        pj = fmaf(beta, pj, rj);
        rs = rsn;
        p_s[tid] = pj;
        __syncthreads();
    }
    out[b * DIM + tid] = -xj;
}

extern "C" void kernel_launch(void* const* d_in, const int* in_sizes, int n_in,
                              void* d_out, int out_size, void* d_ws, size_t ws_size,
                              hipStream_t stream) {
    const float* t_arr = (const float*)d_in[0];
    const float* x_arr = (const float*)d_in[1];
    const float* m0    = (const float*)d_in[2];
    const float* c0    = (const float*)d_in[3];
    float* out = (float*)d_out;
    const int B = in_sizes[0];   // 128
    const size_t need = (size_t)NKK * DIM * 4;   // 512 KB packed fp16
    if (ws_size >= need) {
        hipLaunchKernelGGL(conv_pack_kernel, dim3(NKK * DIM / 256), dim3(256), 0, stream,
                           c0, (unsigned int*)d_ws);
        hipLaunchKernelGGL(vps_solve_kernel, dim3(B), dim3(NTHR), 0, stream,
                           t_arr, x_arr, m0, c0, (const uint4*)d_ws, out);
    } else {
        hipLaunchKernelGGL(vps_cg_kernel, dim3(B), dim3(NTHR), 0, stream,
                           t_arr, x_arr, m0, c0, out);
    }
}

// Round 14
// 92.082 us; speedup vs baseline: 4.2557x; 1.0892x over previous
//
#include <hip/hip_runtime.h>
#include <hip/hip_fp16.h>
#include <math.h>

#define DIM    512
#define NTHR   512
#define NKK    256          // pair-rows (2 matrix rows per pair)
#define SLABKK 72           // pair-rows in LDS (72 * 2KB = 144 KB); % 8 == 0
#define MM     (DIM / 4)    // 128 pair-pair steps
#define S2     (SLABKK / 2) // 36: first streamed pair-pair step

typedef _Float16 h2_t __attribute__((ext_vector_type(2)));

#if defined(__has_builtin)
#  if __has_builtin(__builtin_amdgcn_fdot2)
#    define HAVE_FDOT2 1
#  endif
#endif
#ifndef HAVE_FDOT2
#  define HAVE_FDOT2 0
#endif

// acc += C_pair . p_pair (2 MACs, fp32 accumulate) — proven numerics
__device__ __forceinline__ float dot2acc(unsigned int cu, unsigned int pu, float acc) {
#if HAVE_FDOT2
    return __builtin_amdgcn_fdot2(__builtin_bit_cast(h2_t, cu),
                                  __builtin_bit_cast(h2_t, pu), acc, false);
#else
    const float2 cf = __half22float2(*reinterpret_cast<const __half2*>(&cu));
    const float2 pf = __half22float2(*reinterpret_cast<const __half2*>(&pu));
    return fmaf(cf.y, pf.y, fmaf(cf.x, pf.x, acc));
#endif
}

// fused: acc += dot2(cv0, pu.x) + dot2(cv1, pu.y) over a uint4 pair
#define ACC_STEP(acc, cv0, cv1, pu)                                   \
    do {                                                              \
        (acc).x = dot2acc((cv1).x, (pu).y, dot2acc((cv0).x, (pu).x, (acc).x)); \
        (acc).y = dot2acc((cv1).y, (pu).y, dot2acc((cv0).y, (pu).x, (acc).y)); \
        (acc).z = dot2acc((cv1).z, (pu).y, dot2acc((cv0).z, (pu).x, (acc).z)); \
        (acc).w = dot2acc((cv1).w, (pu).y, dot2acc((cv0).w, (pu).x, (acc).w)); \
    } while (0)

// ---------- 8-wave block sum (phase init only) ----------
__device__ __forceinline__ float block_reduce_sum(float v, float* red) {
    #pragma unroll
    for (int off = 32; off > 0; off >>= 1) v += __shfl_down(v, off, 64);
    const int wid = threadIdx.x >> 6, lane = threadIdx.x & 63;
    __syncthreads();
    if (lane == 0) red[wid] = v;
    __syncthreads();
    float s = 0.f;
    #pragma unroll
    for (int i = 0; i < 8; ++i) s += red[i];
    return s;
}

// ---------- fp32 matvec (refinement residual), proven ----------
__device__ __forceinline__ float matvec_assemble(float4 acc, float4* part, float4* w4_s) {
    const int tid = threadIdx.x;
    __syncthreads();
    part[tid] = acc;
    __syncthreads();
    if (tid < 128) {
        const float4 a0 = part[tid], a1 = part[tid + 128];
        const float4 a2 = part[tid + 256], a3 = part[tid + 384];
        float4 s4;
        s4.x = (a0.x + a1.x) + (a2.x + a3.x);
        s4.y = (a0.y + a1.y) + (a2.y + a3.y);
        s4.z = (a0.z + a1.z) + (a2.z + a3.z);
        s4.w = (a0.w + a1.w) + (a2.w + a3.w);
        w4_s[tid] = s4;
    }
    __syncthreads();
    return reinterpret_cast<const float*>(w4_s)[tid];
}

__device__ __forceinline__ float matvec32(const float4* __restrict__ Cq, const float* p_s,
                                          float4* part, float4* w4_s) {
    const int tid = threadIdx.x;
    const int g = tid >> 7, jq = tid & 127;
    float4 acc = make_float4(0.f, 0.f, 0.f, 0.f);
    int idx = g * 128 + jq;
    #pragma unroll 8
    for (int k = g; k < DIM; k += 4) {
        const float4 cv = Cq[idx];
        const float  pk = p_s[k];
        acc.x = fmaf(pk, cv.x, acc.x);
        acc.y = fmaf(pk, cv.y, acc.y);
        acc.z = fmaf(pk, cv.z, acc.z);
        acc.w = fmaf(pk, cv.w, acc.w);
        idx += 512;
    }
    return matvec_assemble(acc, part, w4_s);
}

// ---------- CG phase: fdot2 matvec, fp16 p, 3 barriers/iter ----------
// Merged 3-dot reduction; rsn = ||r - a w||^2 expanded analytically (exact
// algebra, robust to fp16-p). Depth-6 register prefetch of next-iter stream C
// (12 named uint4; fills the ~0.6 µs reduction window with 96 KB of stream).
__device__ float cg_phase(float bj, float a2, float s2,
                          const uint4* __restrict__ Cg, const uint4* C_lds,
                          unsigned short* p_h, float4* part, float* red,
                          int maxit, float tolf)
{
    const int tid = threadIdx.x;
    const int g   = tid >> 7;
    const int jq  = tid & 127;
    const uint2* p_h64 = (const uint2*)p_h;
    const float* partf = (const float*)part;

    float xj = 0.f, rj = bj, pj = bj;
    __syncthreads();                   // entry fence: prior readers of p_h/part done
    p_h[tid] = __half_as_ushort(__float2half(pj));

    // prologue prefetch: next matvec's first 6 stream steps (C only, no p dep)
    const int m0 = S2 + g, m1 = m0 + 4, m2 = m0 + 8,
              m3 = m0 + 12, m4 = m0 + 16, m5 = m0 + 20;
    uint4 pf0a = Cg[(2 * m0)     * 128 + jq];
    uint4 pf0b = Cg[(2 * m0 + 1) * 128 + jq];
    uint4 pf1a = Cg[(2 * m1)     * 128 + jq];
    uint4 pf1b = Cg[(2 * m1 + 1) * 128 + jq];
    uint4 pf2a = Cg[(2 * m2)     * 128 + jq];
    uint4 pf2b = Cg[(2 * m2 + 1) * 128 + jq];
    uint4 pf3a = Cg[(2 * m3)     * 128 + jq];
    uint4 pf3b = Cg[(2 * m3 + 1) * 128 + jq];
    uint4 pf4a = Cg[(2 * m4)     * 128 + jq];
    uint4 pf4b = Cg[(2 * m4 + 1) * 128 + jq];
    uint4 pf5a = Cg[(2 * m5)     * 128 + jq];
    uint4 pf5b = Cg[(2 * m5 + 1) * 128 + jq];

    float rs = block_reduce_sum(rj * rj, red);    // internal barriers publish p_h
    if (!(rs > 0.f)) return xj;                   // uniform
    const float tol = tolf * rs;

    for (int it = 0; it < maxit; ++it) {
        float4 acc = make_float4(0.f, 0.f, 0.f, 0.f);
        {   // prefetched steps first (registers already resident)
            const uint2 pu0 = p_h64[m0]; ACC_STEP(acc, pf0a, pf0b, pu0);
            const uint2 pu1 = p_h64[m1]; ACC_STEP(acc, pf1a, pf1b, pu1);
            const uint2 pu2 = p_h64[m2]; ACC_STEP(acc, pf2a, pf2b, pu2);
            const uint2 pu3 = p_h64[m3]; ACC_STEP(acc, pf3a, pf3b, pu3);
            const uint2 pu4 = p_h64[m4]; ACC_STEP(acc, pf4a, pf4b, pu4);
            const uint2 pu5 = p_h64[m5]; ACC_STEP(acc, pf5a, pf5b, pu5);
        }
        #pragma unroll
        for (int m = S2 + g + 24; m < MM; m += 4) {  // 17 fresh stream steps
            const uint4 cv0 = Cg[(2 * m)     * 128 + jq];
            const uint4 cv1 = Cg[(2 * m + 1) * 128 + jq];
            const uint2 pu  = p_h64[m];
            ACC_STEP(acc, cv0, cv1, pu);
        }
        #pragma unroll
        for (int m = g; m < S2; m += 4) {            // 9 slab steps from LDS
            const uint4 cv0 = C_lds[(2 * m)     * 128 + jq];
            const uint4 cv1 = C_lds[(2 * m + 1) * 128 + jq];
            const uint2 pu  = p_h64[m];
            ACC_STEP(acc, cv0, cv1, pu);
        }
        part[tid] = acc;

        // refill prefetch for NEXT iteration — issued before barrier A so the
        // vmcnt drain moves these 96 KB into the reduction window.
        pf0a = Cg[(2 * m0)     * 128 + jq];
        pf0b = Cg[(2 * m0 + 1) * 128 + jq];
        pf1a = Cg[(2 * m1)     * 128 + jq];
        pf1b = Cg[(2 * m1 + 1) * 128 + jq];
        pf2a = Cg[(2 * m2)     * 128 + jq];
        pf2b = Cg[(2 * m2 + 1) * 128 + jq];
        pf3a = Cg[(2 * m3)     * 128 + jq];
        pf3b = Cg[(2 * m3 + 1) * 128 + jq];
        pf4a = Cg[(2 * m4)     * 128 + jq];
        pf4b = Cg[(2 * m4 + 1) * 128 + jq];
        pf5a = Cg[(2 * m5)     * 128 + jq];
        pf5b = Cg[(2 * m5 + 1) * 128 + jq];

        __syncthreads();                                   // A: part published

        // self-assembly: w[tid] = sum over 4 groups (2-way bank alias = free)
        const float cw = partf[tid] + partf[512 + tid]
                       + partf[1024 + tid] + partf[1536 + tid];
        const float wj = fmaf(a2, cw, s2 * pj);

        // merged 3-dot partials
        float pwp = pj * wj, rwp = rj * wj, wwp = wj * wj;
        #pragma unroll
        for (int off = 32; off > 0; off >>= 1) {
            pwp += __shfl_down(pwp, off, 64);
            rwp += __shfl_down(rwp, off, 64);
            wwp += __shfl_down(wwp, off, 64);
        }
        if ((tid & 63) == 0) {
            const int w4 = (tid >> 6) * 4;
            red[w4] = pwp; red[w4 + 1] = rwp; red[w4 + 2] = wwp;
        }
        __syncthreads();                                   // B: partials published
        float pw = 0.f, rw = 0.f, ww = 0.f;
        #pragma unroll
        for (int w = 0; w < 8; ++w) {                      // uniform broadcast reads
            pw += red[w * 4]; rw += red[w * 4 + 1]; ww += red[w * 4 + 2];
        }
        pw = fmaxf(pw, 1e-30f);
        const float alpha = rs / pw;
        xj = fmaf( alpha, pj, xj);
        rj = fmaf(-alpha, wj, rj);
        // rsn = ||r_old - alpha w||^2 = rs - 2 a rw + a^2 ww  (exact expansion)
        const float rsn = fmaf(alpha * alpha, ww, fmaf(-2.0f * alpha, rw, rs));
        if (!(rsn > tol)) break;                           // uniform; NaN/neg safe
        const float beta = rsn / rs;
        rs = rsn;
        pj = fmaf(beta, pj, rj);
        p_h[tid] = __half_as_ushort(__float2half(pj));
        __syncthreads();                                   // D: p published
    }
    return xj;
}

// ---------- main solver: one block per item ----------
__global__ __launch_bounds__(NTHR, 1)
void vps_solve_kernel(const float* __restrict__ t_arr,
                      const float* __restrict__ x_arr,
                      const float* __restrict__ mean0,
                      const float* __restrict__ cov0,
                      const uint4* __restrict__ Cp,
                      float* __restrict__ out)
{
    __shared__ uint4  C_lds[SLABKK * 128];                 // 144 KB slab
    __shared__ float4 part[NTHR];                          // 8 KB
    __shared__ float4 p4_s[DIM / 4];                       // 2 KB (refinement p)
    __shared__ float4 w4_s[DIM / 4];                       // 2 KB (refinement w)
    __shared__ __align__(8) unsigned short p_h[DIM];       // 1 KB
    __shared__ float  red[32];
    float* p_s = (float*)p4_s;

    const int b   = blockIdx.x;
    const int tid = threadIdx.x;

    const float t  = t_arr[b];
    const float ib = 0.1f * t + 9.95f * t * t;
    const float a  = expf(-0.5f * ib);
    const float a2 = a * a;
    const float s2 = fmaxf(1.0f - a2, 1e-12f);

    const float rhs = x_arr[b * DIM + tid] - a * mean0[tid];

    // load slab once (coalesced uint4; 18 per thread)
    for (int i = tid; i < SLABKK * 128; i += NTHR) C_lds[i] = Cp[i];
    // cg_phase's entry barriers make the slab visible before the first matvec.

    // Phase 1: CG on fp16 pair-packed matrix (rel-r ~1.1e-1)
    const float x1 = cg_phase(rhs, a2, s2, Cp, C_lds, p_h, part, red, 20, 1.2e-2f);

    // Exact fp32 residual
    __syncthreads();
    p_s[tid] = x1;
    __syncthreads();
    const float cw  = matvec32(reinterpret_cast<const float4*>(cov0), p_s, part, w4_s);
    const float rtj = rhs - (a2 * cw + s2 * x1);

    // Phase 2: correction solve (absorbs fp16 matrix + fp16-p perturbation)
    const float z = cg_phase(rtj, a2, s2, Cp, C_lds, p_h, part, red, 18, 3.5e-2f);

    out[b * DIM + tid] = -(x1 + z);
}

// ---------- pack cov0 -> pair-interleaved fp16 (proven) ----------
__global__ void conv_pack_kernel(const float* __restrict__ C, unsigned int* __restrict__ out) {
    const int id = blockIdx.x * 256 + threadIdx.x;   // 131072 total
    const int kk = id >> 9;
    const int j  = id & 511;
    const __half2 h = __floats2half2_rn(C[(2 * kk) * DIM + j], C[(2 * kk + 1) * DIM + j]);
    out[id] = *reinterpret_cast<const unsigned int*>(&h);
}

// ================= fallback path (ws too small): proven fp32 CG =================
__global__ __launch_bounds__(NTHR, 1)
void vps_cg_kernel(const float* __restrict__ t_arr, const float* __restrict__ x_arr,
                   const float* __restrict__ mean0, const float* __restrict__ cov0,
                   float* __restrict__ out)
{
    const int b = blockIdx.x, tid = threadIdx.x;
    __shared__ float4 part[NTHR];
    __shared__ float4 p4_s[DIM / 4];
    __shared__ float4 w4_s[DIM / 4];
    __shared__ float  red[16];
    float* p_s = (float*)p4_s;
    const float t  = t_arr[b];
    const float ib = 0.1f * t + 9.95f * t * t;
    const float a  = expf(-0.5f * ib);
    const float a2 = a * a;
    const float s2 = fmaxf(1.0f - a2, 1e-12f);
    const float rhs = x_arr[b * DIM + tid] - a * mean0[tid];
    float xj = 0.f, rj = rhs, pj = rhs;
    p_s[tid] = pj;
    float rs = block_reduce_sum(rj * rj, red);
    const float tol = rs * 1e-12f;
    for (int it = 0; it < 72; ++it) {
        const float cw = matvec32(reinterpret_cast<const float4*>(cov0), p_s, part, w4_s);
        const float wj = a2 * cw + s2 * pj;
        const float pw = block_reduce_sum(pj * wj, red);
        const float alpha = rs / fmaxf(pw, 1e-37f);
        xj = fmaf(alpha, pj, xj);
        rj = fmaf(-alpha, wj, rj);
        const float rsn = block_reduce_sum(rj * rj, red);
        if (rsn < tol) break;
        const float beta = rsn / fmaxf(rs, 1e-37f);
        pj = fmaf(beta, pj, rj);
        rs = rsn;
        p_s[tid] = pj;
        __syncthreads();
    }
    out[b * DIM + tid] = -xj;
}

extern "C" void kernel_launch(void* const* d_in, const int* in_sizes, int n_in,
                              void* d_out, int out_size, void* d_ws, size_t ws_size,
                              hipStream_t stream) {
    const float* t_arr = (const float*)d_in[0];
    const float* x_arr = (const float*)d_in[1];
    const float* m0    = (const float*)d_in[2];
    const float* c0    = (const float*)d_in[3];
    float* out = (float*)d_out;
    const int B = in_sizes[0];   // 128
    const size_t need = (size_t)NKK * DIM * 4;   // 512 KB packed fp16
    if (ws_size >= need) {
        hipLaunchKernelGGL(conv_pack_kernel, dim3(NKK * DIM / 256), dim3(256), 0, stream,
                           c0, (unsigned int*)d_ws);
        hipLaunchKernelGGL(vps_solve_kernel, dim3(B), dim3(NTHR), 0, stream,
                           t_arr, x_arr, m0, c0, (const uint4*)d_ws, out);
    } else {
        hipLaunchKernelGGL(vps_cg_kernel, dim3(B), dim3(NTHR), 0, stream,
                           t_arr, x_arr, m0, c0, out);
    }
}